// Round 3
// baseline (3037.112 us; speedup 1.0000x reference)
//
#include <hip/hip_runtime.h>
#include <hip/hip_bf16.h>

// Problem constants (fixed by reference)
#define NN 100000      // nodes
#define NE 800000      // edges
#define EM 100         // embedding dim
#define NL 3           // layers

// ---------------- workspace layout (bytes) ----------------
static constexpr size_t OFF_X    = 0;                               // x      [NN*EM] f32
static constexpr size_t OFF_M    = OFF_X    + (size_t)NN*EM*4;      // m      [NN*EM] f32
static constexpr size_t OFF_F    = OFF_M    + (size_t)NN*EM*4;      // final  [NN*EM] f32
static constexpr size_t OFF_DEG  = OFF_F    + (size_t)NN*EM*4;      // degree [NN] f32
static constexpr size_t OFF_SC   = OFF_DEG  + (size_t)NN*4;         // scores [NN] f32
static constexpr size_t OFF_VALS = OFF_SC   + (size_t)NN*4;         // vals   [NE] f32
static constexpr size_t OFF_ESV  = OFF_VALS + (size_t)NE*4;         // es_val [NE] f32 (CSR-sorted)
static constexpr size_t OFF_ESC  = OFF_ESV  + (size_t)NE*4;         // es_col [NE] i32
static constexpr size_t OFF_CNT  = OFF_ESC  + (size_t)NE*4;         // counts [NN] i32
static constexpr size_t OFF_RP   = OFF_CNT  + (size_t)NN*4;         // rowptr [NN+1] i32
static constexpr size_t OFF_CUR  = OFF_RP   + (size_t)(NN+64)*4;    // cursor [NN] i32
static constexpr size_t OFF_BS   = OFF_CUR  + (size_t)NN*4;         // block sums [128] i32
static constexpr size_t OFF_RED  = OFF_BS   + 512;                  // red[8]: per-layer {max,sum}
static constexpr size_t OFF_FLAG = OFF_RED  + 64;                   // dtype flags [4] i32 (1=f32, 0=bf16)
static constexpr size_t OFF_WAT  = OFF_FLAG + 16;                   // w_att f32 [100]
static constexpr size_t OFF_WI   = OFF_WAT  + 512;                  // w_items f32 [3*100*100]

// dtype-flexible scalar load (prologue kernels only)
__device__ inline float ldf(const void* p, int i, int f32) {
    return f32 ? ((const float*)p)[i]
               : __bfloat162float(((const __hip_bfloat16*)p)[i]);
}

__device__ inline void atomicMaxFloat(float* addr, float val) {
    unsigned int* ia = (unsigned int*)addr;
    unsigned int old = *ia;
    while (__uint_as_float(old) < val) {
        unsigned int assumed = old;
        old = atomicCAS(ia, assumed, __float_as_uint(val));
        if (old == assumed) break;
    }
}

// ---------------- dtype probe ----------------
// Probe EVEN uint16 halves. Little-endian f32 at index k: h[2k] = LOW mantissa
// bits (uniform garbage, ~48% decode with exponent>=134, i.e. |v|>=128 or
// Inf/NaN); h[2k+1] = high half (looks like valid bf16 -- do NOT probe that).
// Genuine bf16 data here (N(0,1), 0.1*N(0,1), U[0,1)) never has |v|>=128.
__global__ __launch_bounds__(64) void k_probe(const void* emb, const void* aval,
                                              const void* watt, const void* witm,
                                              int* flags) {
    int t = threadIdx.x;
    if (t >= 4) return;
    const void* ptrs[4] = {emb, aval, watt, witm};
    const int   ns[4]   = {256, 256, 50, 256};
    const unsigned short* h = (const unsigned short*)ptrs[t];
    int big = 0;
    for (int i = 0; i < ns[t]; i++) {
        int ex = (h[2 * i] >> 7) & 0xFF;
        if (ex >= 134) big++;
    }
    flags[t] = (big >= 2) ? 1 : 0;
}

// ---------------- init / convert ----------------
__global__ __launch_bounds__(256) void k_init(float* deg, int* counts, float* red) {
    int i = blockIdx.x * 256 + threadIdx.x;
    if (i < NN) { deg[i] = 0.f; counts[i] = 0; }
    if (i < 8)  { red[i] = (i & 1) ? 0.f : -1e30f; }  // [2l]=max, [2l+1]=sum
}

__global__ __launch_bounds__(256) void k_cvt(const void* w_att, const void* w_itm,
                                             const int* flags, float* wat, float* wi) {
    int i = blockIdx.x * 256 + threadIdx.x;
    if (i < NL * EM * EM) wi[i] = ldf(w_itm, i, flags[3]);
    if (i < EM)           wat[i] = ldf(w_att, i, flags[2]);
}

__global__ __launch_bounds__(256) void k_initxf(const void* __restrict__ emb, const int* flags,
                                                float* __restrict__ x, float* __restrict__ fin) {
    int i = blockIdx.x * 256 + threadIdx.x;
    if (i >= NN * EM) return;
    float v = ldf(emb, i, flags[0]);
    x[i] = v; fin[i] = v;
}

// ---------------- degree + row histogram ----------------
__global__ __launch_bounds__(256) void k_deg(const void* __restrict__ val,
                                             const int* __restrict__ row, const int* __restrict__ col,
                                             const int* flags, float* deg, int* counts) {
    int e = blockIdx.x * 256 + threadIdx.x;
    if (e >= NE) return;
    atomicAdd(&deg[col[e]], ldf(val, e, flags[1]));
    atomicAdd(&counts[row[e]], 1);
}

__global__ __launch_bounds__(256) void k_vals(const void* __restrict__ val,
                                              const int* __restrict__ col, const int* flags,
                                              const float* __restrict__ deg, float* vals) {
    int e = blockIdx.x * 256 + threadIdx.x;
    if (e >= NE) return;
    vals[e] = ldf(val, e, flags[1]) / deg[col[e]];
}

// ---------------- exclusive scan of counts -> rowptr (3 kernels) ----------------
__global__ __launch_bounds__(256) void k_scanA(const int* __restrict__ counts, int* excl, int* bsum) {
    __shared__ int s[256];
    int base = blockIdx.x * 1024;
    int tid = threadIdx.x;
    int v[4]; int t = 0;
    #pragma unroll
    for (int i = 0; i < 4; i++) {
        int idx = base + tid * 4 + i;
        v[i] = (idx < NN) ? counts[idx] : 0;
        t += v[i];
    }
    s[tid] = t; __syncthreads();
    for (int off = 1; off < 256; off <<= 1) {
        int add = (tid >= off) ? s[tid - off] : 0;
        __syncthreads();
        s[tid] += add;
        __syncthreads();
    }
    int ex = (tid == 0) ? 0 : s[tid - 1];
    #pragma unroll
    for (int i = 0; i < 4; i++) {
        int idx = base + tid * 4 + i;
        if (idx < NN) excl[idx] = ex;
        ex += v[i];
    }
    if (tid == 255) bsum[blockIdx.x] = s[255];
}

__global__ __launch_bounds__(64) void k_scanB(int* bsum, int nb) {
    if (threadIdx.x == 0) {
        int run = 0;
        for (int i = 0; i < nb; i++) { int t = bsum[i]; bsum[i] = run; run += t; }
    }
}

__global__ __launch_bounds__(256) void k_scanC(int* rowptr, int* cursor, const int* __restrict__ bsum) {
    int i = blockIdx.x * 256 + threadIdx.x;
    if (i >= NN) return;
    int v = rowptr[i] + bsum[i >> 10];
    rowptr[i] = v; cursor[i] = v;
    if (i == 0) rowptr[NN] = NE;
}

__global__ __launch_bounds__(256) void k_scatter(const int* __restrict__ row, const int* __restrict__ col,
                                                 const float* __restrict__ vals, int* cursor,
                                                 int* es_col, float* es_val) {
    int e = blockIdx.x * 256 + threadIdx.x;
    if (e >= NE) return;
    int r = row[e];
    int pos = atomicAdd(&cursor[r], 1);
    es_col[pos] = col[e];
    es_val[pos] = vals[e];
}

// ---------------- per-layer: attention scores + softmax ----------------
// NOTE: b_att is omitted everywhere -- softmax over nodes is invariant to a
// uniform additive shift, so the bias cancels exactly.
__global__ __launch_bounds__(256) void k_scores(const float* __restrict__ x,
                                                const float* __restrict__ wat,
                                                float* __restrict__ scores, float* red, int layer) {
    __shared__ float smax[4];
    int lane = threadIdx.x & 63, w = threadIdx.x >> 6;
    int n = blockIdx.x * 4 + w;
    float part = 0.f, sc = -1e30f;
    if (n < NN) {
        const float* xp = x + (size_t)n * EM;
        part = xp[lane] * wat[lane];
        if (lane < 36) part += xp[64 + lane] * wat[64 + lane];
    }
    #pragma unroll
    for (int off = 32; off; off >>= 1) part += __shfl_xor(part, off);
    if (n < NN) {
        sc = part;
        if (lane == 0) scores[n] = sc;
    }
    if (lane == 0) smax[w] = sc;
    __syncthreads();
    if (threadIdx.x == 0) {
        float mx = fmaxf(fmaxf(smax[0], smax[1]), fmaxf(smax[2], smax[3]));
        atomicMaxFloat(&red[2 * layer], mx);
    }
}

__global__ __launch_bounds__(256) void k_expsum(float* __restrict__ scores, float* red, int layer) {
    __shared__ float ss[4];
    int n = blockIdx.x * 256 + threadIdx.x;
    float M = red[2 * layer];
    float p = 0.f;
    if (n < NN) { p = expf(scores[n] - M); scores[n] = p; }
    float t = p;
    #pragma unroll
    for (int off = 32; off; off >>= 1) t += __shfl_xor(t, off);
    if ((threadIdx.x & 63) == 0) ss[threadIdx.x >> 6] = t;
    __syncthreads();
    if (threadIdx.x == 0) atomicAdd(&red[2 * layer + 1], ss[0] + ss[1] + ss[2] + ss[3]);
}

// ---------------- per-layer: m = (x @ W^T) * attw ----------------
// block: 256 thr, 64 rows; W staged k-major in LDS padded to 128 cols; 8x4 micro-tile.
__global__ __launch_bounds__(256, 2) void k_gemm(const float* __restrict__ x,
                                                 const float* __restrict__ wi,
                                                 const float* __restrict__ scores,
                                                 const float* __restrict__ red,
                                                 float* __restrict__ m, int layer) {
    __shared__ float Ws[100 * 128];
    __shared__ float xs[64 * 100];
    int tid = threadIdx.x;
    int base = blockIdx.x * 64;
    const float* W = wi + (size_t)layer * EM * EM;
    for (int idx = tid; idx < EM * EM; idx += 256) {
        int j = idx / EM, k = idx - EM * j;
        Ws[k * 128 + j] = W[idx];   // transpose: Ws[k][j] = W[j][k]
    }
    for (int idx = tid; idx < EM * 28; idx += 256) {
        int k = idx / 28, j = 100 + (idx - 28 * k);
        Ws[k * 128 + j] = 0.f;
    }
    const float4* xg4 = (const float4*)x;
    float4* xs4 = (float4*)xs;
    int nrow = NN - base; if (nrow > 64) nrow = 64;
    int nf4 = nrow * 25;
    for (int idx = tid; idx < 1600; idx += 256)
        xs4[idx] = (idx < nf4) ? xg4[(size_t)base * 25 + idx] : make_float4(0.f, 0.f, 0.f, 0.f);
    __syncthreads();

    float inv_sum = 1.0f / red[2 * layer + 1];
    int tx = tid & 31, ty = tid >> 5;
    int j0 = tx * 4;
    int rbase = ty * 8;
    float acc[8][4];
    #pragma unroll
    for (int r = 0; r < 8; r++)
        #pragma unroll
        for (int c = 0; c < 4; c++) acc[r][c] = 0.f;
    const float4* Ws4 = (const float4*)Ws;
    for (int kq = 0; kq < 25; kq++) {
        float4 wv[4];
        #pragma unroll
        for (int t = 0; t < 4; t++) wv[t] = Ws4[(kq * 4 + t) * 32 + tx];
        #pragma unroll
        for (int r = 0; r < 8; r++) {
            float4 xv = xs4[(rbase + r) * 25 + kq];
            acc[r][0] += xv.x * wv[0].x + xv.y * wv[1].x + xv.z * wv[2].x + xv.w * wv[3].x;
            acc[r][1] += xv.x * wv[0].y + xv.y * wv[1].y + xv.z * wv[2].y + xv.w * wv[3].y;
            acc[r][2] += xv.x * wv[0].z + xv.y * wv[1].z + xv.z * wv[2].z + xv.w * wv[3].z;
            acc[r][3] += xv.x * wv[0].w + xv.y * wv[1].w + xv.z * wv[2].w + xv.w * wv[3].w;
        }
    }
    if (j0 < EM) {
        #pragma unroll
        for (int r = 0; r < 8; r++) {
            int grow = base + rbase + r;
            if (grow < NN) {
                float att = scores[grow] * inv_sum;
                float4 o;
                o.x = acc[r][0] * att; o.y = acc[r][1] * att;
                o.z = acc[r][2] * att; o.w = acc[r][3] * att;
                *(float4*)(&m[(size_t)grow * EM + j0]) = o;
            }
        }
    }
}

// ---------------- per-layer: SpMM (gather, CSR) fused with L2-normalize + final += ----------------
__global__ __launch_bounds__(256) void k_spmm(const int* __restrict__ rowptr,
                                              const int* __restrict__ es_col,
                                              const float* __restrict__ es_val,
                                              const float* __restrict__ m,
                                              float* __restrict__ x, float* __restrict__ fin) {
    int lane = threadIdx.x & 63;
    int w = threadIdx.x >> 6;
    int r = blockIdx.x * 4 + w;
    if (r >= NN) return;
    int s = rowptr[r], e = rowptr[r + 1];
    float a0 = 0.f, a1 = 0.f;
    bool lo = lane < 36;
    for (int i = s; i < e; i++) {
        int c = es_col[i];
        float v = es_val[i];
        const float* mp = m + (size_t)c * EM;
        a0 += v * mp[lane];
        if (lo) a1 += v * mp[64 + lane];
    }
    float sq = a0 * a0 + a1 * a1;
    #pragma unroll
    for (int off = 32; off; off >>= 1) sq += __shfl_xor(sq, off);
    float rn = 1.f / fmaxf(sqrtf(sq), 1e-12f);
    float n0 = a0 * rn, n1 = a1 * rn;
    float* xp = x + (size_t)r * EM;
    float* fp = fin + (size_t)r * EM;
    xp[lane] = n0; fp[lane] += n0;
    if (lo) { xp[64 + lane] = n1; fp[64 + lane] += n1; }
}

// ---------------- output: out = final / 4, dtype per flags[0] ----------------
__global__ __launch_bounds__(256) void k_out(const float* __restrict__ fin, const int* flags,
                                             void* __restrict__ out) {
    int i = blockIdx.x * 256 + threadIdx.x;
    if (i >= NN * EM) return;
    float v = fin[i] * 0.25f;
    if (flags[0]) ((float*)out)[i] = v;
    else          ((__hip_bfloat16*)out)[i] = __float2bfloat16(v);
}

extern "C" void kernel_launch(void* const* d_in, const int* in_sizes, int n_in,
                              void* d_out, int out_size, void* d_ws, size_t ws_size,
                              hipStream_t stream) {
    const void* emb   = d_in[0];
    const void* aval  = d_in[1];
    const void* w_att = d_in[2];
    const void* w_itm = d_in[4];
    const int* arow = (const int*)d_in[5];
    const int* acol = (const int*)d_in[6];

    char* w = (char*)d_ws;
    float* x      = (float*)(w + OFF_X);
    float* m      = (float*)(w + OFF_M);
    float* fin    = (float*)(w + OFF_F);
    float* deg    = (float*)(w + OFF_DEG);
    float* scores = (float*)(w + OFF_SC);
    float* vals   = (float*)(w + OFF_VALS);
    float* es_val = (float*)(w + OFF_ESV);
    int*   es_col = (int*)  (w + OFF_ESC);
    int*   counts = (int*)  (w + OFF_CNT);
    int*   rowptr = (int*)  (w + OFF_RP);
    int*   cursor = (int*)  (w + OFF_CUR);
    int*   bsum   = (int*)  (w + OFF_BS);
    float* red    = (float*)(w + OFF_RED);
    int*   flags  = (int*)  (w + OFF_FLAG);
    float* wat    = (float*)(w + OFF_WAT);
    float* wi     = (float*)(w + OFF_WI);

    const int GN   = (NN + 255) / 256;        // 391
    const int GNE  = (NE + 255) / 256;        // 3125
    const int GNEM = (NN * EM + 255) / 256;   // 39063
    const int GSCN = (NN + 1023) / 1024;      // 98 scan blocks
    const int GW4  = (NN + 3) / 4;            // 25000 (wave-per-node kernels)
    const int GGE  = (NN + 63) / 64;          // 1563 gemm blocks
    const int GCVT = (NL * EM * EM + 255) / 256;

    k_probe<<<1, 64, 0, stream>>>(emb, aval, w_att, w_itm, flags);
    k_init<<<GN, 256, 0, stream>>>(deg, counts, red);
    k_cvt<<<GCVT, 256, 0, stream>>>(w_att, w_itm, flags, wat, wi);
    k_initxf<<<GNEM, 256, 0, stream>>>(emb, flags, x, fin);
    k_deg<<<GNE, 256, 0, stream>>>(aval, arow, acol, flags, deg, counts);
    k_vals<<<GNE, 256, 0, stream>>>(aval, acol, flags, deg, vals);
    k_scanA<<<GSCN, 256, 0, stream>>>(counts, rowptr, bsum);
    k_scanB<<<1, 64, 0, stream>>>(bsum, GSCN);
    k_scanC<<<GN, 256, 0, stream>>>(rowptr, cursor, bsum);
    k_scatter<<<GNE, 256, 0, stream>>>(arow, acol, vals, cursor, es_col, es_val);

    for (int l = 0; l < NL; l++) {
        k_scores<<<GW4, 256, 0, stream>>>(x, wat, scores, red, l);
        k_expsum<<<GN, 256, 0, stream>>>(scores, red, l);
        k_gemm<<<GGE, 256, 0, stream>>>(x, wi, scores, red, m, l);
        k_spmm<<<GW4, 256, 0, stream>>>(rowptr, es_col, es_val, m, x, fin);
    }
    k_out<<<GNEM, 256, 0, stream>>>(fin, flags, d_out);
}

// Round 4
// 908.072 us; speedup vs baseline: 3.3446x; 3.3446x over previous
//
#include <hip/hip_runtime.h>
#include <hip/hip_bf16.h>

// Problem constants (fixed by reference)
#define NN 100000      // nodes
#define NE 800000      // edges
#define EM 100         // embedding dim
#define NL 3           // layers

// ---------------- workspace layout (bytes) ----------------
static constexpr size_t OFF_X    = 0;                               // x      [NN*EM] f32
static constexpr size_t OFF_M    = OFF_X    + (size_t)NN*EM*4;      // m      [NN*EM] f32
static constexpr size_t OFF_F    = OFF_M    + (size_t)NN*EM*4;      // final  [NN*EM] f32
static constexpr size_t OFF_DEG  = OFF_F    + (size_t)NN*EM*4;      // degree [NN] f32
static constexpr size_t OFF_SC   = OFF_DEG  + (size_t)NN*4;         // scores [NN] f32
static constexpr size_t OFF_VALS = OFF_SC   + (size_t)NN*4;         // vals   [NE] f32
static constexpr size_t OFF_ESV  = OFF_VALS + (size_t)NE*4;         // es_val [NE] f32 (CSR-sorted)
static constexpr size_t OFF_ESC  = OFF_ESV  + (size_t)NE*4;         // es_col [NE] i32
static constexpr size_t OFF_CNT  = OFF_ESC  + (size_t)NE*4;         // counts [NN] i32
static constexpr size_t OFF_RP   = OFF_CNT  + (size_t)NN*4;         // rowptr [NN+1] i32
static constexpr size_t OFF_CUR  = OFF_RP   + (size_t)(NN+64)*4;    // cursor [NN] i32
static constexpr size_t OFF_BS   = OFF_CUR  + (size_t)NN*4;         // block sums [128] i32
static constexpr size_t OFF_RED  = OFF_BS   + 512;                  // red[8]: per-layer {unused,sum}
static constexpr size_t OFF_FLAG = OFF_RED  + 64;                   // dtype flags [4] i32 (1=f32, 0=bf16)
static constexpr size_t OFF_WAT  = OFF_FLAG + 16;                   // w_att f32 [100]
static constexpr size_t OFF_WI   = OFF_WAT  + 512;                  // w_items f32 [3*100*100]

// dtype-flexible scalar load (prologue kernels only)
__device__ inline float ldf(const void* p, int i, int f32) {
    return f32 ? ((const float*)p)[i]
               : __bfloat162float(((const __hip_bfloat16*)p)[i]);
}

// ---------------- dtype probe ----------------
// Probe EVEN uint16 halves. Little-endian f32 at index k: h[2k] = LOW mantissa
// bits (uniform garbage, ~48% decode with exponent>=134); genuine bf16 data
// here never has |v|>=128. h[2k+1] is the HIGH half of an f32 (= its bf16
// truncation) so it is useless for discrimination -- probe even halves only.
__global__ __launch_bounds__(64) void k_probe(const void* emb, const void* aval,
                                              const void* watt, const void* witm,
                                              int* flags) {
    int t = threadIdx.x;
    if (t >= 4) return;
    const void* ptrs[4] = {emb, aval, watt, witm};
    const int   ns[4]   = {256, 256, 50, 256};
    const unsigned short* h = (const unsigned short*)ptrs[t];
    int big = 0;
    for (int i = 0; i < ns[t]; i++) {
        int ex = (h[2 * i] >> 7) & 0xFF;
        if (ex >= 134) big++;
    }
    flags[t] = (big >= 2) ? 1 : 0;
}

// ---------------- init / convert ----------------
__global__ __launch_bounds__(256) void k_init(float* deg, int* counts, float* red) {
    int i = blockIdx.x * 256 + threadIdx.x;
    if (i < NN) { deg[i] = 0.f; counts[i] = 0; }
    if (i < 8)  { red[i] = 0.f; }   // [2l+1] = softmax denom accumulator
}

__global__ __launch_bounds__(256) void k_cvt(const void* w_att, const void* w_itm,
                                             const int* flags, float* wat, float* wi) {
    int i = blockIdx.x * 256 + threadIdx.x;
    if (i < NL * EM * EM) wi[i] = ldf(w_itm, i, flags[3]);
    if (i < EM)           wat[i] = ldf(w_att, i, flags[2]);
}

__global__ __launch_bounds__(256) void k_initxf(const void* __restrict__ emb, const int* flags,
                                                float* __restrict__ x, float* __restrict__ fin) {
    int i = blockIdx.x * 256 + threadIdx.x;
    if (i >= NN * EM) return;
    float v = ldf(emb, i, flags[0]);
    x[i] = v; fin[i] = v;
}

// ---------------- degree + row histogram ----------------
__global__ __launch_bounds__(256) void k_deg(const void* __restrict__ val,
                                             const int* __restrict__ row, const int* __restrict__ col,
                                             const int* flags, float* deg, int* counts) {
    int e = blockIdx.x * 256 + threadIdx.x;
    if (e >= NE) return;
    atomicAdd(&deg[col[e]], ldf(val, e, flags[1]));
    atomicAdd(&counts[row[e]], 1);
}

__global__ __launch_bounds__(256) void k_vals(const void* __restrict__ val,
                                              const int* __restrict__ col, const int* flags,
                                              const float* __restrict__ deg, float* vals) {
    int e = blockIdx.x * 256 + threadIdx.x;
    if (e >= NE) return;
    vals[e] = ldf(val, e, flags[1]) / deg[col[e]];
}

// ---------------- exclusive scan of counts -> rowptr (3 kernels) ----------------
__global__ __launch_bounds__(256) void k_scanA(const int* __restrict__ counts, int* excl, int* bsum) {
    __shared__ int s[256];
    int base = blockIdx.x * 1024;
    int tid = threadIdx.x;
    int v[4]; int t = 0;
    #pragma unroll
    for (int i = 0; i < 4; i++) {
        int idx = base + tid * 4 + i;
        v[i] = (idx < NN) ? counts[idx] : 0;
        t += v[i];
    }
    s[tid] = t; __syncthreads();
    for (int off = 1; off < 256; off <<= 1) {
        int add = (tid >= off) ? s[tid - off] : 0;
        __syncthreads();
        s[tid] += add;
        __syncthreads();
    }
    int ex = (tid == 0) ? 0 : s[tid - 1];
    #pragma unroll
    for (int i = 0; i < 4; i++) {
        int idx = base + tid * 4 + i;
        if (idx < NN) excl[idx] = ex;
        ex += v[i];
    }
    if (tid == 255) bsum[blockIdx.x] = s[255];
}

__global__ __launch_bounds__(64) void k_scanB(int* bsum, int nb) {
    if (threadIdx.x == 0) {
        int run = 0;
        for (int i = 0; i < nb; i++) { int t = bsum[i]; bsum[i] = run; run += t; }
    }
}

__global__ __launch_bounds__(256) void k_scanC(int* rowptr, int* cursor, const int* __restrict__ bsum) {
    int i = blockIdx.x * 256 + threadIdx.x;
    if (i >= NN) return;
    int v = rowptr[i] + bsum[i >> 10];
    rowptr[i] = v; cursor[i] = v;
    if (i == 0) rowptr[NN] = NE;
}

__global__ __launch_bounds__(256) void k_scatter(const int* __restrict__ row, const int* __restrict__ col,
                                                 const float* __restrict__ vals, int* cursor,
                                                 int* es_col, float* es_val) {
    int e = blockIdx.x * 256 + threadIdx.x;
    if (e >= NE) return;
    int r = row[e];
    int pos = atomicAdd(&cursor[r], 1);
    es_col[pos] = col[e];
    es_val[pos] = vals[e];
}

// ---------------- per-layer: attention scores ----------------
// b_att omitted (softmax shift-invariance). No max subtraction: scores are
// bounded (|s| <~ 5 layer 0; <= ~1 after L2-normalize) so exp() is safe, and
// softmax is mathematically identical. This removes the single-address
// atomicCAS spin that cost ~800us/layer in round 3 (25k blocks ping-ponging
// one line across 8 non-coherent XCD L2s; VALUBusy 1%, HBM 0.4%).
__global__ __launch_bounds__(256) void k_scores(const float* __restrict__ x,
                                                const float* __restrict__ wat,
                                                float* __restrict__ scores) {
    int lane = threadIdx.x & 63, w = threadIdx.x >> 6;
    int n = blockIdx.x * 4 + w;
    if (n >= NN) return;
    const float* xp = x + (size_t)n * EM;
    float part = xp[lane] * wat[lane];
    if (lane < 36) part += xp[64 + lane] * wat[64 + lane];
    #pragma unroll
    for (int off = 32; off; off >>= 1) part += __shfl_xor(part, off);
    if (lane == 0) scores[n] = part;
}

// exp (M=0) + global sum: 391 blocks -> 391 atomics, cheap.
__global__ __launch_bounds__(256) void k_expsum(float* __restrict__ scores, float* red, int layer) {
    __shared__ float ss[4];
    int n = blockIdx.x * 256 + threadIdx.x;
    float p = 0.f;
    if (n < NN) { p = expf(scores[n]); scores[n] = p; }
    float t = p;
    #pragma unroll
    for (int off = 32; off; off >>= 1) t += __shfl_xor(t, off);
    if ((threadIdx.x & 63) == 0) ss[threadIdx.x >> 6] = t;
    __syncthreads();
    if (threadIdx.x == 0) atomicAdd(&red[2 * layer + 1], ss[0] + ss[1] + ss[2] + ss[3]);
}

// ---------------- per-layer: m = (x @ W^T) * attw ----------------
// block: 256 thr, 64 rows; W staged k-major in LDS padded to 128 cols; 8x4 micro-tile.
__global__ __launch_bounds__(256, 2) void k_gemm(const float* __restrict__ x,
                                                 const float* __restrict__ wi,
                                                 const float* __restrict__ scores,
                                                 const float* __restrict__ red,
                                                 float* __restrict__ m, int layer) {
    __shared__ float Ws[100 * 128];
    __shared__ float xs[64 * 100];
    int tid = threadIdx.x;
    int base = blockIdx.x * 64;
    const float* W = wi + (size_t)layer * EM * EM;
    for (int idx = tid; idx < EM * EM; idx += 256) {
        int j = idx / EM, k = idx - EM * j;
        Ws[k * 128 + j] = W[idx];   // transpose: Ws[k][j] = W[j][k]
    }
    for (int idx = tid; idx < EM * 28; idx += 256) {
        int k = idx / 28, j = 100 + (idx - 28 * k);
        Ws[k * 128 + j] = 0.f;
    }
    const float4* xg4 = (const float4*)x;
    float4* xs4 = (float4*)xs;
    int nrow = NN - base; if (nrow > 64) nrow = 64;
    int nf4 = nrow * 25;
    for (int idx = tid; idx < 1600; idx += 256)
        xs4[idx] = (idx < nf4) ? xg4[(size_t)base * 25 + idx] : make_float4(0.f, 0.f, 0.f, 0.f);
    __syncthreads();

    float inv_sum = 1.0f / red[2 * layer + 1];
    int tx = tid & 31, ty = tid >> 5;
    int j0 = tx * 4;
    int rbase = ty * 8;
    float acc[8][4];
    #pragma unroll
    for (int r = 0; r < 8; r++)
        #pragma unroll
        for (int c = 0; c < 4; c++) acc[r][c] = 0.f;
    const float4* Ws4 = (const float4*)Ws;
    for (int kq = 0; kq < 25; kq++) {
        float4 wv[4];
        #pragma unroll
        for (int t = 0; t < 4; t++) wv[t] = Ws4[(kq * 4 + t) * 32 + tx];
        #pragma unroll
        for (int r = 0; r < 8; r++) {
            float4 xv = xs4[(rbase + r) * 25 + kq];
            acc[r][0] += xv.x * wv[0].x + xv.y * wv[1].x + xv.z * wv[2].x + xv.w * wv[3].x;
            acc[r][1] += xv.x * wv[0].y + xv.y * wv[1].y + xv.z * wv[2].y + xv.w * wv[3].y;
            acc[r][2] += xv.x * wv[0].z + xv.y * wv[1].z + xv.z * wv[2].z + xv.w * wv[3].z;
            acc[r][3] += xv.x * wv[0].w + xv.y * wv[1].w + xv.z * wv[2].w + xv.w * wv[3].w;
        }
    }
    if (j0 < EM) {
        #pragma unroll
        for (int r = 0; r < 8; r++) {
            int grow = base + rbase + r;
            if (grow < NN) {
                float att = scores[grow] * inv_sum;
                float4 o;
                o.x = acc[r][0] * att; o.y = acc[r][1] * att;
                o.z = acc[r][2] * att; o.w = acc[r][3] * att;
                *(float4*)(&m[(size_t)grow * EM + j0]) = o;
            }
        }
    }
}

// ---------------- per-layer: SpMM (gather, CSR) fused with L2-normalize + final += ----------------
__global__ __launch_bounds__(256) void k_spmm(const int* __restrict__ rowptr,
                                              const int* __restrict__ es_col,
                                              const float* __restrict__ es_val,
                                              const float* __restrict__ m,
                                              float* __restrict__ x, float* __restrict__ fin) {
    int lane = threadIdx.x & 63;
    int w = threadIdx.x >> 6;
    int r = blockIdx.x * 4 + w;
    if (r >= NN) return;
    int s = rowptr[r], e = rowptr[r + 1];
    float a0 = 0.f, a1 = 0.f;
    bool lo = lane < 36;
    for (int i = s; i < e; i++) {
        int c = es_col[i];
        float v = es_val[i];
        const float* mp = m + (size_t)c * EM;
        a0 += v * mp[lane];
        if (lo) a1 += v * mp[64 + lane];
    }
    float sq = a0 * a0 + a1 * a1;
    #pragma unroll
    for (int off = 32; off; off >>= 1) sq += __shfl_xor(sq, off);
    float rn = 1.f / fmaxf(sqrtf(sq), 1e-12f);
    float n0 = a0 * rn, n1 = a1 * rn;
    float* xp = x + (size_t)r * EM;
    float* fp = fin + (size_t)r * EM;
    xp[lane] = n0; fp[lane] += n0;
    if (lo) { xp[64 + lane] = n1; fp[64 + lane] += n1; }
}

// ---------------- output: out = final / 4, dtype per flags[0] ----------------
__global__ __launch_bounds__(256) void k_out(const float* __restrict__ fin, const int* flags,
                                             void* __restrict__ out) {
    int i = blockIdx.x * 256 + threadIdx.x;
    if (i >= NN * EM) return;
    float v = fin[i] * 0.25f;
    if (flags[0]) ((float*)out)[i] = v;
    else          ((__hip_bfloat16*)out)[i] = __float2bfloat16(v);
}

extern "C" void kernel_launch(void* const* d_in, const int* in_sizes, int n_in,
                              void* d_out, int out_size, void* d_ws, size_t ws_size,
                              hipStream_t stream) {
    const void* emb   = d_in[0];
    const void* aval  = d_in[1];
    const void* w_att = d_in[2];
    const void* w_itm = d_in[4];
    const int* arow = (const int*)d_in[5];
    const int* acol = (const int*)d_in[6];

    char* w = (char*)d_ws;
    float* x      = (float*)(w + OFF_X);
    float* m      = (float*)(w + OFF_M);
    float* fin    = (float*)(w + OFF_F);
    float* deg    = (float*)(w + OFF_DEG);
    float* scores = (float*)(w + OFF_SC);
    float* vals   = (float*)(w + OFF_VALS);
    float* es_val = (float*)(w + OFF_ESV);
    int*   es_col = (int*)  (w + OFF_ESC);
    int*   counts = (int*)  (w + OFF_CNT);
    int*   rowptr = (int*)  (w + OFF_RP);
    int*   cursor = (int*)  (w + OFF_CUR);
    int*   bsum   = (int*)  (w + OFF_BS);
    float* red    = (float*)(w + OFF_RED);
    int*   flags  = (int*)  (w + OFF_FLAG);
    float* wat    = (float*)(w + OFF_WAT);
    float* wi     = (float*)(w + OFF_WI);

    const int GN   = (NN + 255) / 256;        // 391
    const int GNE  = (NE + 255) / 256;        // 3125
    const int GNEM = (NN * EM + 255) / 256;   // 39063
    const int GSCN = (NN + 1023) / 1024;      // 98 scan blocks
    const int GW4  = (NN + 3) / 4;            // 25000 (wave-per-node kernels)
    const int GGE  = (NN + 63) / 64;          // 1563 gemm blocks
    const int GCVT = (NL * EM * EM + 255) / 256;

    k_probe<<<1, 64, 0, stream>>>(emb, aval, w_att, w_itm, flags);
    k_init<<<GN, 256, 0, stream>>>(deg, counts, red);
    k_cvt<<<GCVT, 256, 0, stream>>>(w_att, w_itm, flags, wat, wi);
    k_initxf<<<GNEM, 256, 0, stream>>>(emb, flags, x, fin);
    k_deg<<<GNE, 256, 0, stream>>>(aval, arow, acol, flags, deg, counts);
    k_vals<<<GNE, 256, 0, stream>>>(aval, acol, flags, deg, vals);
    k_scanA<<<GSCN, 256, 0, stream>>>(counts, rowptr, bsum);
    k_scanB<<<1, 64, 0, stream>>>(bsum, GSCN);
    k_scanC<<<GN, 256, 0, stream>>>(rowptr, cursor, bsum);
    k_scatter<<<GNE, 256, 0, stream>>>(arow, acol, vals, cursor, es_col, es_val);

    for (int l = 0; l < NL; l++) {
        k_scores<<<GW4, 256, 0, stream>>>(x, wat, scores);
        k_expsum<<<GN, 256, 0, stream>>>(scores, red, l);
        k_gemm<<<GGE, 256, 0, stream>>>(x, wi, scores, red, m, l);
        k_spmm<<<GW4, 256, 0, stream>>>(rowptr, es_col, es_val, m, x, fin);
    }
    k_out<<<GNEM, 256, 0, stream>>>(fin, flags, d_out);
}

// Round 5
// 819.937 us; speedup vs baseline: 3.7041x; 1.1075x over previous
//
#include <hip/hip_runtime.h>
#include <hip/hip_bf16.h>

// Problem constants (fixed by reference)
#define NN 100000      // nodes
#define NE 800000      // edges
#define EM 100         // embedding dim
#define NL 3           // layers

// ---------------- workspace layout (bytes) ----------------
static constexpr size_t OFF_X    = 0;                               // x      [NN*EM] f32
static constexpr size_t OFF_M    = OFF_X    + (size_t)NN*EM*4;      // m      [NN*EM] bf16
static constexpr size_t OFF_F    = OFF_M    + (size_t)NN*EM*2;      // final  [NN*EM] bf16
static constexpr size_t OFF_DEG  = OFF_F    + (size_t)NN*EM*2;      // degree [NN] f32
static constexpr size_t OFF_SC   = OFF_DEG  + (size_t)NN*4;         // scores [NN] f32
static constexpr size_t OFF_ESV  = OFF_SC   + (size_t)NN*4;         // es_val [NE] f32 (CSR-sorted)
static constexpr size_t OFF_ESC  = OFF_ESV  + (size_t)NE*4;         // es_col [NE] i32
static constexpr size_t OFF_CNT  = OFF_ESC  + (size_t)NE*4;         // counts [NN] i32
static constexpr size_t OFF_RP   = OFF_CNT  + (size_t)NN*4;         // rowptr [NN+1] i32
static constexpr size_t OFF_CUR  = OFF_RP   + (size_t)(NN+64)*4;    // cursor [NN] i32
static constexpr size_t OFF_BS   = OFF_CUR  + (size_t)NN*4;         // block sums [128] i32
static constexpr size_t OFF_RED  = OFF_BS   + 512;                  // red[8]: per-layer {unused,sum}
static constexpr size_t OFF_FLAG = OFF_RED  + 64;                   // dtype flags [4] i32 (1=f32, 0=bf16)
static constexpr size_t OFF_WAT  = OFF_FLAG + 16;                   // w_att f32 [100]
static constexpr size_t OFF_WI   = OFF_WAT  + 512;                  // w_items f32 [3*100*100]

// dtype-flexible scalar load (prologue kernels only)
__device__ inline float ldf(const void* p, int i, int f32) {
    return f32 ? ((const float*)p)[i]
               : __bfloat162float(((const __hip_bfloat16*)p)[i]);
}

// unpack a packed pair of bf16 (little-endian: low ushort = element 0)
__device__ inline float bflo(unsigned int u) { return __uint_as_float(u << 16); }
__device__ inline float bfhi(unsigned int u) { return __uint_as_float(u & 0xFFFF0000u); }
// pack two floats to bf16 pair (RNE via __float2bfloat16)
__device__ inline unsigned int pack2bf(float a, float b) {
    __hip_bfloat16 ha = __float2bfloat16(a), hb = __float2bfloat16(b);
    unsigned short ua = *(unsigned short*)&ha, ub = *(unsigned short*)&hb;
    return (unsigned int)ua | ((unsigned int)ub << 16);
}

// ---------------- dtype probe ----------------
// Probe EVEN uint16 halves. Little-endian f32 at index k: h[2k] = LOW mantissa
// bits (uniform garbage, ~48% decode with exponent>=134); genuine bf16 data
// here never has |v|>=128. h[2k+1] is the HIGH half of an f32 (= its bf16
// truncation) so it is useless for discrimination -- probe even halves only.
__global__ __launch_bounds__(64) void k_probe(const void* emb, const void* aval,
                                              const void* watt, const void* witm,
                                              int* flags) {
    int t = threadIdx.x;
    if (t >= 4) return;
    const void* ptrs[4] = {emb, aval, watt, witm};
    const int   ns[4]   = {256, 256, 50, 256};
    const unsigned short* h = (const unsigned short*)ptrs[t];
    int big = 0;
    for (int i = 0; i < ns[t]; i++) {
        int ex = (h[2 * i] >> 7) & 0xFF;
        if (ex >= 134) big++;
    }
    flags[t] = (big >= 2) ? 1 : 0;
}

// ---------------- init / convert ----------------
__global__ __launch_bounds__(256) void k_init(float* deg, int* counts, float* red) {
    int i = blockIdx.x * 256 + threadIdx.x;
    if (i < NN) { deg[i] = 0.f; counts[i] = 0; }
    if (i < 8)  { red[i] = 0.f; }   // [2l+1] = softmax denom accumulator
}

__global__ __launch_bounds__(256) void k_cvt(const void* w_att, const void* w_itm,
                                             const int* flags, float* wat, float* wi) {
    int i = blockIdx.x * 256 + threadIdx.x;
    if (i < NL * EM * EM) wi[i] = ldf(w_itm, i, flags[3]);
    if (i < EM)           wat[i] = ldf(w_att, i, flags[2]);
}

// wave-per-row: x=emb (f32), fin=emb (bf16), scores[r]=dot(emb_row, w_att).
// (b_att omitted everywhere: softmax over nodes is shift-invariant.)
__global__ __launch_bounds__(256) void k_initxf(const void* __restrict__ emb, const int* flags,
                                                const float* __restrict__ wat,
                                                float* __restrict__ x, unsigned int* __restrict__ fin,
                                                float* __restrict__ scores) {
    int lane = threadIdx.x & 63, w = threadIdx.x >> 6;
    int r = blockIdx.x * 4 + w;
    if (r >= NN) return;
    float f0 = 0.f, f1 = 0.f, part = 0.f;
    bool act = lane < 50;
    if (act) {
        if (flags[0]) {
            float2 t = ((const float2*)emb)[(size_t)r * 50 + lane];
            f0 = t.x; f1 = t.y;
        } else {
            unsigned int u = ((const unsigned int*)emb)[(size_t)r * 50 + lane];
            f0 = bflo(u); f1 = bfhi(u);
        }
        float2 wv = *(const float2*)(wat + 2 * lane);
        part = f0 * wv.x + f1 * wv.y;
        ((float2*)x)[(size_t)r * 50 + lane] = make_float2(f0, f1);
        fin[(size_t)r * 50 + lane] = pack2bf(f0, f1);
    }
    #pragma unroll
    for (int off = 32; off; off >>= 1) part += __shfl_xor(part, off);
    if (lane == 0) scores[r] = part;
}

// ---------------- degree + row histogram ----------------
__global__ __launch_bounds__(256) void k_deg(const void* __restrict__ val,
                                             const int* __restrict__ row, const int* __restrict__ col,
                                             const int* flags, float* deg, int* counts) {
    int e = blockIdx.x * 256 + threadIdx.x;
    if (e >= NE) return;
    atomicAdd(&deg[col[e]], ldf(val, e, flags[1]));
    atomicAdd(&counts[row[e]], 1);
}

// ---------------- exclusive scan of counts -> rowptr (3 kernels) ----------------
__global__ __launch_bounds__(256) void k_scanA(const int* __restrict__ counts, int* excl, int* bsum) {
    __shared__ int s[256];
    int base = blockIdx.x * 1024;
    int tid = threadIdx.x;
    int v[4]; int t = 0;
    #pragma unroll
    for (int i = 0; i < 4; i++) {
        int idx = base + tid * 4 + i;
        v[i] = (idx < NN) ? counts[idx] : 0;
        t += v[i];
    }
    s[tid] = t; __syncthreads();
    for (int off = 1; off < 256; off <<= 1) {
        int add = (tid >= off) ? s[tid - off] : 0;
        __syncthreads();
        s[tid] += add;
        __syncthreads();
    }
    int ex = (tid == 0) ? 0 : s[tid - 1];
    #pragma unroll
    for (int i = 0; i < 4; i++) {
        int idx = base + tid * 4 + i;
        if (idx < NN) excl[idx] = ex;
        ex += v[i];
    }
    if (tid == 255) bsum[blockIdx.x] = s[255];
}

__global__ __launch_bounds__(64) void k_scanB(int* bsum, int nb) {
    if (threadIdx.x == 0) {
        int run = 0;
        for (int i = 0; i < nb; i++) { int t = bsum[i]; bsum[i] = run; run += t; }
    }
}

__global__ __launch_bounds__(256) void k_scanC(int* rowptr, int* cursor, const int* __restrict__ bsum) {
    int i = blockIdx.x * 256 + threadIdx.x;
    if (i >= NN) return;
    int v = rowptr[i] + bsum[i >> 10];
    rowptr[i] = v; cursor[i] = v;
    if (i == 0) rowptr[NN] = NE;
}

// scatter edges into CSR order; fuses the old k_vals (val/deg[col]) inline.
__global__ __launch_bounds__(256) void k_scatter(const int* __restrict__ row, const int* __restrict__ col,
                                                 const void* __restrict__ aval, const int* flags,
                                                 const float* __restrict__ deg, int* cursor,
                                                 int* es_col, float* es_val) {
    int e = blockIdx.x * 256 + threadIdx.x;
    if (e >= NE) return;
    int r = row[e];
    int c = col[e];
    int pos = atomicAdd(&cursor[r], 1);
    es_col[pos] = c;
    es_val[pos] = ldf(aval, e, flags[1]) / deg[c];
}

// exp (no max subtraction: scores bounded, softmax identical) + global sum.
__global__ __launch_bounds__(256) void k_expsum(float* __restrict__ scores, float* red, int layer) {
    __shared__ float ss[4];
    int n = blockIdx.x * 256 + threadIdx.x;
    float p = 0.f;
    if (n < NN) { p = expf(scores[n]); scores[n] = p; }
    float t = p;
    #pragma unroll
    for (int off = 32; off; off >>= 1) t += __shfl_xor(t, off);
    if ((threadIdx.x & 63) == 0) ss[threadIdx.x >> 6] = t;
    __syncthreads();
    if (threadIdx.x == 0) atomicAdd(&red[2 * layer + 1], ss[0] + ss[1] + ss[2] + ss[3]);
}

// ---------------- per-layer: m = bf16((x @ W^T) * attw) ----------------
// block: 256 thr, 64 rows; W staged k-major in LDS padded to 128 cols; 8x4 micro-tile.
__global__ __launch_bounds__(256, 2) void k_gemm(const float* __restrict__ x,
                                                 const float* __restrict__ wi,
                                                 const float* __restrict__ scores,
                                                 const float* __restrict__ red,
                                                 unsigned short* __restrict__ m, int layer) {
    __shared__ float Ws[100 * 128];
    __shared__ float xs[64 * 100];
    int tid = threadIdx.x;
    int base = blockIdx.x * 64;
    const float* W = wi + (size_t)layer * EM * EM;
    for (int idx = tid; idx < EM * EM; idx += 256) {
        int j = idx / EM, k = idx - EM * j;
        Ws[k * 128 + j] = W[idx];   // transpose: Ws[k][j] = W[j][k]
    }
    for (int idx = tid; idx < EM * 28; idx += 256) {
        int k = idx / 28, j = 100 + (idx - 28 * k);
        Ws[k * 128 + j] = 0.f;
    }
    const float4* xg4 = (const float4*)x;
    float4* xs4 = (float4*)xs;
    int nrow = NN - base; if (nrow > 64) nrow = 64;
    int nf4 = nrow * 25;
    for (int idx = tid; idx < 1600; idx += 256)
        xs4[idx] = (idx < nf4) ? xg4[(size_t)base * 25 + idx] : make_float4(0.f, 0.f, 0.f, 0.f);
    __syncthreads();

    float inv_sum = 1.0f / red[2 * layer + 1];
    int tx = tid & 31, ty = tid >> 5;
    int j0 = tx * 4;
    int rbase = ty * 8;
    float acc[8][4];
    #pragma unroll
    for (int r = 0; r < 8; r++)
        #pragma unroll
        for (int c = 0; c < 4; c++) acc[r][c] = 0.f;
    const float4* Ws4 = (const float4*)Ws;
    for (int kq = 0; kq < 25; kq++) {
        float4 wv[4];
        #pragma unroll
        for (int t = 0; t < 4; t++) wv[t] = Ws4[(kq * 4 + t) * 32 + tx];
        #pragma unroll
        for (int r = 0; r < 8; r++) {
            float4 xv = xs4[(rbase + r) * 25 + kq];
            acc[r][0] += xv.x * wv[0].x + xv.y * wv[1].x + xv.z * wv[2].x + xv.w * wv[3].x;
            acc[r][1] += xv.x * wv[0].y + xv.y * wv[1].y + xv.z * wv[2].y + xv.w * wv[3].y;
            acc[r][2] += xv.x * wv[0].z + xv.y * wv[1].z + xv.z * wv[2].z + xv.w * wv[3].z;
            acc[r][3] += xv.x * wv[0].w + xv.y * wv[1].w + xv.z * wv[2].w + xv.w * wv[3].w;
        }
    }
    if (j0 < EM) {
        #pragma unroll
        for (int r = 0; r < 8; r++) {
            int grow = base + rbase + r;
            if (grow < NN) {
                float att = scores[grow] * inv_sum;
                ushort4 o;
                __hip_bfloat16 b0 = __float2bfloat16(acc[r][0] * att);
                __hip_bfloat16 b1 = __float2bfloat16(acc[r][1] * att);
                __hip_bfloat16 b2 = __float2bfloat16(acc[r][2] * att);
                __hip_bfloat16 b3 = __float2bfloat16(acc[r][3] * att);
                o.x = *(unsigned short*)&b0; o.y = *(unsigned short*)&b1;
                o.z = *(unsigned short*)&b2; o.w = *(unsigned short*)&b3;
                *(ushort4*)(&m[(size_t)grow * EM + j0]) = o;
            }
        }
    }
}

// ---------------- per-layer: SpMM (bf16 gather, CSR) fused with L2-normalize,
// final += (bf16 rmw), next-layer scores, and (last layer) output write.
__global__ __launch_bounds__(256) void k_spmm(const int* __restrict__ rowptr,
                                              const int* __restrict__ es_col,
                                              const float* __restrict__ es_val,
                                              const unsigned short* __restrict__ m,
                                              const float* __restrict__ wat,
                                              float* __restrict__ x, unsigned int* __restrict__ fin,
                                              float* __restrict__ scores,
                                              void* __restrict__ out, const int* flags, int last) {
    int lane = threadIdx.x & 63;
    int w = threadIdx.x >> 6;
    int r = blockIdx.x * 4 + w;
    if (r >= NN) return;
    int s = rowptr[r], e = rowptr[r + 1];
    float a0 = 0.f, a1 = 0.f;
    bool act = lane < 50;
    for (int i = s; i < e; i++) {
        int c = es_col[i];
        float v = es_val[i];
        if (act) {
            unsigned int u = *(const unsigned int*)(m + (size_t)c * EM + 2 * lane);
            a0 += v * bflo(u);
            a1 += v * bfhi(u);
        }
    }
    float sq = a0 * a0 + a1 * a1;
    #pragma unroll
    for (int off = 32; off; off >>= 1) sq += __shfl_xor(sq, off);
    float rn = 1.f / fmaxf(sqrtf(sq), 1e-12f);
    float n0 = a0 * rn, n1 = a1 * rn;

    float part = 0.f;
    if (act) {
        size_t pidx = (size_t)r * 50 + lane;
        unsigned int fu = fin[pidx];
        float fn0 = bflo(fu) + n0, fn1 = bfhi(fu) + n1;
        if (!last) {
            ((float2*)x)[pidx] = make_float2(n0, n1);
            fin[pidx] = pack2bf(fn0, fn1);
            float2 wv = *(const float2*)(wat + 2 * lane);
            part = n0 * wv.x + n1 * wv.y;
        } else {
            float o0 = fn0 * 0.25f, o1 = fn1 * 0.25f;
            if (flags[0]) ((float2*)out)[pidx] = make_float2(o0, o1);
            else          ((unsigned int*)out)[pidx] = pack2bf(o0, o1);
        }
    }
    if (!last) {
        #pragma unroll
        for (int off = 32; off; off >>= 1) part += __shfl_xor(part, off);
        if (lane == 0) scores[r] = part;
    }
}

extern "C" void kernel_launch(void* const* d_in, const int* in_sizes, int n_in,
                              void* d_out, int out_size, void* d_ws, size_t ws_size,
                              hipStream_t stream) {
    const void* emb   = d_in[0];
    const void* aval  = d_in[1];
    const void* w_att = d_in[2];
    const void* w_itm = d_in[4];
    const int* arow = (const int*)d_in[5];
    const int* acol = (const int*)d_in[6];

    char* w = (char*)d_ws;
    float*          x      = (float*)(w + OFF_X);
    unsigned short* m      = (unsigned short*)(w + OFF_M);
    unsigned int*   fin    = (unsigned int*)(w + OFF_F);
    float*          deg    = (float*)(w + OFF_DEG);
    float*          scores = (float*)(w + OFF_SC);
    float*          es_val = (float*)(w + OFF_ESV);
    int*            es_col = (int*)  (w + OFF_ESC);
    int*            counts = (int*)  (w + OFF_CNT);
    int*            rowptr = (int*)  (w + OFF_RP);
    int*            cursor = (int*)  (w + OFF_CUR);
    int*            bsum   = (int*)  (w + OFF_BS);
    float*          red    = (float*)(w + OFF_RED);
    int*            flags  = (int*)  (w + OFF_FLAG);
    float*          wat    = (float*)(w + OFF_WAT);
    float*          wi     = (float*)(w + OFF_WI);

    const int GN   = (NN + 255) / 256;        // 391
    const int GNE  = (NE + 255) / 256;        // 3125
    const int GSCN = (NN + 1023) / 1024;      // 98 scan blocks
    const int GW4  = (NN + 3) / 4;            // 25000 (wave-per-node kernels)
    const int GGE  = (NN + 63) / 64;          // 1563 gemm blocks
    const int GCVT = (NL * EM * EM + 255) / 256;

    k_probe<<<1, 64, 0, stream>>>(emb, aval, w_att, w_itm, flags);
    k_init<<<GN, 256, 0, stream>>>(deg, counts, red);
    k_cvt<<<GCVT, 256, 0, stream>>>(w_att, w_itm, flags, wat, wi);
    k_initxf<<<GW4, 256, 0, stream>>>(emb, flags, wat, x, fin, scores);
    k_deg<<<GNE, 256, 0, stream>>>(aval, arow, acol, flags, deg, counts);
    k_scanA<<<GSCN, 256, 0, stream>>>(counts, rowptr, bsum);
    k_scanB<<<1, 64, 0, stream>>>(bsum, GSCN);
    k_scanC<<<GN, 256, 0, stream>>>(rowptr, cursor, bsum);
    k_scatter<<<GNE, 256, 0, stream>>>(arow, acol, aval, flags, deg, cursor, es_col, es_val);

    for (int l = 0; l < NL; l++) {
        k_expsum<<<GN, 256, 0, stream>>>(scores, red, l);
        k_gemm<<<GGE, 256, 0, stream>>>(x, wi, scores, red, m, l);
        k_spmm<<<GW4, 256, 0, stream>>>(rowptr, es_col, es_val, m, wat, x, fin, scores,
                                        d_out, flags, (l == NL - 1) ? 1 : 0);
    }
}

// Round 8
// 747.396 us; speedup vs baseline: 4.0636x; 1.0971x over previous
//
#include <hip/hip_runtime.h>
#include <hip/hip_bf16.h>

// Problem constants (fixed by reference)
#define NN 100000      // nodes
#define NE 800000      // edges
#define EM 100         // embedding dim
#define NL 3           // layers

// ---------------- workspace layout (bytes) ----------------
static constexpr size_t OFF_X    = 0;                               // x      [NN*EM] f32
static constexpr size_t OFF_M    = OFF_X    + (size_t)NN*EM*4;      // m      [NN*EM] bf16
static constexpr size_t OFF_F    = OFF_M    + (size_t)NN*EM*2;      // final  [NN*EM] bf16
static constexpr size_t OFF_DEG  = OFF_F    + (size_t)NN*EM*2;      // degree [NN] f32
static constexpr size_t OFF_SC   = OFF_DEG  + (size_t)NN*4;         // scores [NN] f32
static constexpr size_t OFF_ES   = OFF_SC   + (size_t)NN*4;         // es     [NE] int2 {col, val bits}
static constexpr size_t OFF_CNT  = OFF_ES   + (size_t)NE*8;         // counts [NN] i32
static constexpr size_t OFF_RP   = OFF_CNT  + (size_t)NN*4;         // rowptr [NN+1] i32
static constexpr size_t OFF_CUR  = OFF_RP   + (size_t)(NN+64)*4;    // cursor [NN] i32
static constexpr size_t OFF_BS   = OFF_CUR  + (size_t)NN*4;         // block sums [128] i32
static constexpr size_t OFF_RED  = OFF_BS   + 512;                  // red[8]: per-layer {unused,sum}
static constexpr size_t OFF_FLAG = OFF_RED  + 64;                   // dtype flags [4] i32 (1=f32, 0=bf16)
static constexpr size_t OFF_WAT  = OFF_FLAG + 16;                   // w_att f32 [100]
static constexpr size_t OFF_WI   = OFF_WAT  + 512;                  // w_items f32 [3*100*100]

// dtype-flexible scalar load (prologue kernels only)
__device__ inline float ldf(const void* p, int i, int f32) {
    return f32 ? ((const float*)p)[i]
               : __bfloat162float(((const __hip_bfloat16*)p)[i]);
}

// unpack a packed pair of bf16 (little-endian: low ushort = element 0)
__device__ inline float bflo(unsigned int u) { return __uint_as_float(u << 16); }
__device__ inline float bfhi(unsigned int u) { return __uint_as_float(u & 0xFFFF0000u); }
// pack two floats to bf16 pair (RNE via __float2bfloat16)
__device__ inline unsigned int pack2bf(float a, float b) {
    __hip_bfloat16 ha = __float2bfloat16(a), hb = __float2bfloat16(b);
    unsigned short ua = *(unsigned short*)&ha, ub = *(unsigned short*)&hb;
    return (unsigned int)ua | ((unsigned int)ub << 16);
}

// ---------------- dtype probe ----------------
// Probe EVEN uint16 halves. Little-endian f32 at index k: h[2k] = LOW mantissa
// bits (uniform garbage, ~48% decode with exponent>=134); genuine bf16 data
// here never has |v|>=128. h[2k+1] is the HIGH half of an f32 (= its bf16
// truncation) so it is useless for discrimination -- probe even halves only.
__global__ __launch_bounds__(64) void k_probe(const void* emb, const void* aval,
                                              const void* watt, const void* witm,
                                              int* flags) {
    int t = threadIdx.x;
    if (t >= 4) return;
    const void* ptrs[4] = {emb, aval, watt, witm};
    const int   ns[4]   = {256, 256, 50, 256};
    const unsigned short* h = (const unsigned short*)ptrs[t];
    int big = 0;
    for (int i = 0; i < ns[t]; i++) {
        int ex = (h[2 * i] >> 7) & 0xFF;
        if (ex >= 134) big++;
    }
    flags[t] = (big >= 2) ? 1 : 0;
}

// ---------------- init / convert ----------------
__global__ __launch_bounds__(256) void k_init(float* deg, int* counts, float* red) {
    int i = blockIdx.x * 256 + threadIdx.x;
    if (i < NN) { deg[i] = 0.f; counts[i] = 0; }
    if (i < 8)  { red[i] = 0.f; }   // [2l+1] = softmax denom accumulator
}

__global__ __launch_bounds__(256) void k_cvt(const void* w_att, const void* w_itm,
                                             const int* flags, float* wat, float* wi) {
    int i = blockIdx.x * 256 + threadIdx.x;
    if (i < NL * EM * EM) wi[i] = ldf(w_itm, i, flags[3]);
    if (i < EM)           wat[i] = ldf(w_att, i, flags[2]);
}

// wave-per-row: x=emb (f32), fin=emb (bf16), scores[r]=dot(emb_row, w_att).
// (b_att omitted everywhere: softmax over nodes is shift-invariant.)
__global__ __launch_bounds__(256) void k_initxf(const void* __restrict__ emb, const int* flags,
                                                const float* __restrict__ wat,
                                                float* __restrict__ x, unsigned int* __restrict__ fin,
                                                float* __restrict__ scores) {
    int lane = threadIdx.x & 63, w = threadIdx.x >> 6;
    int r = blockIdx.x * 4 + w;
    if (r >= NN) return;
    float f0 = 0.f, f1 = 0.f, part = 0.f;
    bool act = lane < 50;
    if (act) {
        if (flags[0]) {
            float2 t = ((const float2*)emb)[(size_t)r * 50 + lane];
            f0 = t.x; f1 = t.y;
        } else {
            unsigned int u = ((const unsigned int*)emb)[(size_t)r * 50 + lane];
            f0 = bflo(u); f1 = bfhi(u);
        }
        float2 wv = *(const float2*)(wat + 2 * lane);
        part = f0 * wv.x + f1 * wv.y;
        ((float2*)x)[(size_t)r * 50 + lane] = make_float2(f0, f1);
        fin[(size_t)r * 50 + lane] = pack2bf(f0, f1);
    }
    #pragma unroll
    for (int off = 32; off; off >>= 1) part += __shfl_xor(part, off);
    if (lane == 0) scores[r] = part;
}

// ---------------- degree + row histogram ----------------
__global__ __launch_bounds__(256) void k_deg(const void* __restrict__ val,
                                             const int* __restrict__ row, const int* __restrict__ col,
                                             const int* flags, float* deg, int* counts) {
    int e = blockIdx.x * 256 + threadIdx.x;
    if (e >= NE) return;
    atomicAdd(&deg[col[e]], ldf(val, e, flags[1]));
    atomicAdd(&counts[row[e]], 1);
}

// ---------------- exclusive scan of counts -> rowptr (3 kernels) ----------------
__global__ __launch_bounds__(256) void k_scanA(const int* __restrict__ counts, int* excl, int* bsum) {
    __shared__ int s[256];
    int base = blockIdx.x * 1024;
    int tid = threadIdx.x;
    int v[4]; int t = 0;
    #pragma unroll
    for (int i = 0; i < 4; i++) {
        int idx = base + tid * 4 + i;
        v[i] = (idx < NN) ? counts[idx] : 0;
        t += v[i];
    }
    s[tid] = t; __syncthreads();
    for (int off = 1; off < 256; off <<= 1) {
        int add = (tid >= off) ? s[tid - off] : 0;
        __syncthreads();
        s[tid] += add;
        __syncthreads();
    }
    int ex = (tid == 0) ? 0 : s[tid - 1];
    #pragma unroll
    for (int i = 0; i < 4; i++) {
        int idx = base + tid * 4 + i;
        if (idx < NN) excl[idx] = ex;
        ex += v[i];
    }
    if (tid == 255) bsum[blockIdx.x] = s[255];
}

__global__ __launch_bounds__(64) void k_scanB(int* bsum, int nb) {
    if (threadIdx.x == 0) {
        int run = 0;
        for (int i = 0; i < nb; i++) { int t = bsum[i]; bsum[i] = run; run += t; }
    }
}

__global__ __launch_bounds__(256) void k_scanC(int* rowptr, int* cursor, const int* __restrict__ bsum) {
    int i = blockIdx.x * 256 + threadIdx.x;
    if (i >= NN) return;
    int v = rowptr[i] + bsum[i >> 10];
    rowptr[i] = v; cursor[i] = v;
    if (i == 0) rowptr[NN] = NE;
}

// scatter edges into CSR order; packs {col, val/deg[col]} into one int2.
__global__ __launch_bounds__(256) void k_scatter(const int* __restrict__ row, const int* __restrict__ col,
                                                 const void* __restrict__ aval, const int* flags,
                                                 const float* __restrict__ deg, int* cursor,
                                                 int2* es) {
    int e = blockIdx.x * 256 + threadIdx.x;
    if (e >= NE) return;
    int r = row[e];
    int c = col[e];
    int pos = atomicAdd(&cursor[r], 1);
    float v = ldf(aval, e, flags[1]) / deg[c];
    es[pos] = make_int2(c, __float_as_int(v));
}

// exp (no max subtraction: scores bounded, softmax identical) + global sum.
__global__ __launch_bounds__(256) void k_expsum(float* __restrict__ scores, float* red, int layer) {
    __shared__ float ss[4];
    int n = blockIdx.x * 256 + threadIdx.x;
    float p = 0.f;
    if (n < NN) { p = expf(scores[n]); scores[n] = p; }
    float t = p;
    #pragma unroll
    for (int off = 32; off; off >>= 1) t += __shfl_xor(t, off);
    if ((threadIdx.x & 63) == 0) ss[threadIdx.x >> 6] = t;
    __syncthreads();
    if (threadIdx.x == 0) atomicAdd(&red[2 * layer + 1], ss[0] + ss[1] + ss[2] + ss[3]);
}

// ---------------- per-layer: m = bf16((x @ W^T) * attw) ----------------
// block: 256 thr, 64 rows; W staged k-major in LDS padded to 128 cols; 8x4 micro-tile.
__global__ __launch_bounds__(256, 2) void k_gemm(const float* __restrict__ x,
                                                 const float* __restrict__ wi,
                                                 const float* __restrict__ scores,
                                                 const float* __restrict__ red,
                                                 unsigned short* __restrict__ m, int layer) {
    __shared__ float Ws[100 * 128];
    __shared__ float xs[64 * 100];
    int tid = threadIdx.x;
    int base = blockIdx.x * 64;
    const float* W = wi + (size_t)layer * EM * EM;
    for (int idx = tid; idx < EM * EM; idx += 256) {
        int j = idx / EM, k = idx - EM * j;
        Ws[k * 128 + j] = W[idx];   // transpose: Ws[k][j] = W[j][k]
    }
    for (int idx = tid; idx < EM * 28; idx += 256) {
        int k = idx / 28, j = 100 + (idx - 28 * k);
        Ws[k * 128 + j] = 0.f;
    }
    const float4* xg4 = (const float4*)x;
    float4* xs4 = (float4*)xs;
    int nrow = NN - base; if (nrow > 64) nrow = 64;
    int nf4 = nrow * 25;
    for (int idx = tid; idx < 1600; idx += 256)
        xs4[idx] = (idx < nf4) ? xg4[(size_t)base * 25 + idx] : make_float4(0.f, 0.f, 0.f, 0.f);
    __syncthreads();

    float inv_sum = 1.0f / red[2 * layer + 1];
    int tx = tid & 31, ty = tid >> 5;
    int j0 = tx * 4;
    int rbase = ty * 8;
    float acc[8][4];
    #pragma unroll
    for (int r = 0; r < 8; r++)
        #pragma unroll
        for (int c = 0; c < 4; c++) acc[r][c] = 0.f;
    const float4* Ws4 = (const float4*)Ws;
    for (int kq = 0; kq < 25; kq++) {
        float4 wv[4];
        #pragma unroll
        for (int t = 0; t < 4; t++) wv[t] = Ws4[(kq * 4 + t) * 32 + tx];
        #pragma unroll
        for (int r = 0; r < 8; r++) {
            float4 xv = xs4[(rbase + r) * 25 + kq];
            acc[r][0] += xv.x * wv[0].x + xv.y * wv[1].x + xv.z * wv[2].x + xv.w * wv[3].x;
            acc[r][1] += xv.x * wv[0].y + xv.y * wv[1].y + xv.z * wv[2].y + xv.w * wv[3].y;
            acc[r][2] += xv.x * wv[0].z + xv.y * wv[1].z + xv.z * wv[2].z + xv.w * wv[3].z;
            acc[r][3] += xv.x * wv[0].w + xv.y * wv[1].w + xv.z * wv[2].w + xv.w * wv[3].w;
        }
    }
    if (j0 < EM) {
        #pragma unroll
        for (int r = 0; r < 8; r++) {
            int grow = base + rbase + r;
            if (grow < NN) {
                float att = scores[grow] * inv_sum;
                ushort4 o;
                __hip_bfloat16 b0 = __float2bfloat16(acc[r][0] * att);
                __hip_bfloat16 b1 = __float2bfloat16(acc[r][1] * att);
                __hip_bfloat16 b2 = __float2bfloat16(acc[r][2] * att);
                __hip_bfloat16 b3 = __float2bfloat16(acc[r][3] * att);
                o.x = *(unsigned short*)&b0; o.y = *(unsigned short*)&b1;
                o.z = *(unsigned short*)&b2; o.w = *(unsigned short*)&b3;
                *(ushort4*)(&m[(size_t)grow * EM + j0]) = o;
            }
        }
    }
}

// ---------------- per-layer: SpMM (bf16 gather, CSR) fused with L2-normalize,
// final += (bf16 rmw), next-layer scores, and (last layer) output write.
// Predicated unroll-4 edge loop -- 4 independent gathers in flight per batch
// (round 5 showed duration invariant to bytes => latency-chain bound, one
// dependent gather per iteration). Out-of-range slots reuse the batch's
// first column with weight 0 (no serial remainder).
__global__ __launch_bounds__(256) void k_spmm(const int* __restrict__ rowptr,
                                              const int2* __restrict__ es,
                                              const unsigned short* __restrict__ m,
                                              const float* __restrict__ wat,
                                              float* __restrict__ x, unsigned int* __restrict__ fin,
                                              float* __restrict__ scores,
                                              void* __restrict__ out, const int* flags, int last) {
    int lane = threadIdx.x & 63;
    int w = threadIdx.x >> 6;
    int r = blockIdx.x * 4 + w;
    if (r >= NN) return;
    int s = rowptr[r], e = rowptr[r + 1];
    bool act = lane < 50;
    float a0 = 0.f, a1 = 0.f, b0 = 0.f, b1 = 0.f;
    for (int i = s; i < e; i += 4) {
        int2 cv[4];
        cv[0] = es[i];
        #pragma unroll
        for (int j = 1; j < 4; j++)
            cv[j] = (i + j < e) ? es[i + j] : make_int2(cv[0].x, 0);
        unsigned int u[4] = {0u, 0u, 0u, 0u};
        if (act) {
            #pragma unroll
            for (int j = 0; j < 4; j++)
                u[j] = *(const unsigned int*)(m + (size_t)cv[j].x * EM + 2 * lane);
        }
        float v0 = __int_as_float(cv[0].y), v1 = __int_as_float(cv[1].y);
        float v2 = __int_as_float(cv[2].y), v3 = __int_as_float(cv[3].y);
        a0 += v0 * bflo(u[0]); a1 += v0 * bfhi(u[0]);
        b0 += v1 * bflo(u[1]); b1 += v1 * bfhi(u[1]);
        a0 += v2 * bflo(u[2]); a1 += v2 * bfhi(u[2]);
        b0 += v3 * bflo(u[3]); b1 += v3 * bfhi(u[3]);
    }
    a0 += b0; a1 += b1;
    float sq = a0 * a0 + a1 * a1;
    #pragma unroll
    for (int off = 32; off; off >>= 1) sq += __shfl_xor(sq, off);
    float rn = 1.f / fmaxf(sqrtf(sq), 1e-12f);
    float n0 = a0 * rn, n1 = a1 * rn;

    float part = 0.f;
    if (act) {
        size_t pidx = (size_t)r * 50 + lane;
        unsigned int fu = fin[pidx];
        float fn0 = bflo(fu) + n0, fn1 = bfhi(fu) + n1;
        if (!last) {
            ((float2*)x)[pidx] = make_float2(n0, n1);
            fin[pidx] = pack2bf(fn0, fn1);
            float2 wv = *(const float2*)(wat + 2 * lane);
            part = n0 * wv.x + n1 * wv.y;
        } else {
            float o0 = fn0 * 0.25f, o1 = fn1 * 0.25f;
            if (flags[0]) ((float2*)out)[pidx] = make_float2(o0, o1);
            else          ((unsigned int*)out)[pidx] = pack2bf(o0, o1);
        }
    }
    if (!last) {
        #pragma unroll
        for (int off = 32; off; off >>= 1) part += __shfl_xor(part, off);
        if (lane == 0) scores[r] = part;
    }
}

extern "C" void kernel_launch(void* const* d_in, const int* in_sizes, int n_in,
                              void* d_out, int out_size, void* d_ws, size_t ws_size,
                              hipStream_t stream) {
    const void* emb   = d_in[0];
    const void* aval  = d_in[1];
    const void* w_att = d_in[2];
    const void* w_itm = d_in[4];
    const int* arow = (const int*)d_in[5];
    const int* acol = (const int*)d_in[6];

    char* w = (char*)d_ws;
    float*          x      = (float*)(w + OFF_X);
    unsigned short* m      = (unsigned short*)(w + OFF_M);
    unsigned int*   fin    = (unsigned int*)(w + OFF_F);
    float*          deg    = (float*)(w + OFF_DEG);
    float*          scores = (float*)(w + OFF_SC);
    int2*           es     = (int2*) (w + OFF_ES);
    int*            counts = (int*)  (w + OFF_CNT);
    int*            rowptr = (int*)  (w + OFF_RP);
    int*            cursor = (int*)  (w + OFF_CUR);
    int*            bsum   = (int*)  (w + OFF_BS);
    float*          red    = (float*)(w + OFF_RED);
    int*            flags  = (int*)  (w + OFF_FLAG);
    float*          wat    = (float*)(w + OFF_WAT);
    float*          wi     = (float*)(w + OFF_WI);

    const int GN   = (NN + 255) / 256;        // 391
    const int GNE  = (NE + 255) / 256;        // 3125
    const int GSCN = (NN + 1023) / 1024;      // 98 scan blocks
    const int GW4  = (NN + 3) / 4;            // 25000 (wave-per-node kernels)
    const int GGE  = (NN + 63) / 64;          // 1563 gemm blocks
    const int GCVT = (NL * EM * EM + 255) / 256;

    k_probe<<<1, 64, 0, stream>>>(emb, aval, w_att, w_itm, flags);
    k_init<<<GN, 256, 0, stream>>>(deg, counts, red);
    k_cvt<<<GCVT, 256, 0, stream>>>(w_att, w_itm, flags, wat, wi);
    k_initxf<<<GW4, 256, 0, stream>>>(emb, flags, wat, x, fin, scores);
    k_deg<<<GNE, 256, 0, stream>>>(aval, arow, acol, flags, deg, counts);
    k_scanA<<<GSCN, 256, 0, stream>>>(counts, rowptr, bsum);
    k_scanB<<<1, 64, 0, stream>>>(bsum, GSCN);
    k_scanC<<<GN, 256, 0, stream>>>(rowptr, cursor, bsum);
    k_scatter<<<GNE, 256, 0, stream>>>(arow, acol, aval, flags, deg, cursor, es);

    for (int l = 0; l < NL; l++) {
        k_expsum<<<GN, 256, 0, stream>>>(scores, red, l);
        k_gemm<<<GGE, 256, 0, stream>>>(x, wi, scores, red, m, l);
        k_spmm<<<GW4, 256, 0, stream>>>(rowptr, es, m, wat, x, fin, scores,
                                        d_out, flags, (l == NL - 1) ? 1 : 0);
    }
}

// Round 9
// 604.598 us; speedup vs baseline: 5.0234x; 1.2362x over previous
//
#include <hip/hip_runtime.h>
#include <hip/hip_bf16.h>

// Problem constants (fixed by reference)
#define NN 100000      // nodes
#define NE 800000      // edges
#define EM 100         // embedding dim
#define NL 3           // layers

typedef short bf16x8 __attribute__((ext_vector_type(8)));
typedef float f32x4  __attribute__((ext_vector_type(4)));

// ---------------- workspace layout (bytes) ----------------
static constexpr size_t OFF_XB   = 0;                               // xbf [NN*128] bf16 (K-padded rows)
static constexpr size_t OFF_M    = OFF_XB   + (size_t)NN*128*2;     // m   [NN*100] bf16
static constexpr size_t OFF_F    = OFF_M    + (size_t)NN*EM*2;      // fin [NN*50] uint (bf16x2)
static constexpr size_t OFF_DEG  = OFF_F    + (size_t)NN*EM*2;      // degree [NN] f32
static constexpr size_t OFF_SC   = OFF_DEG  + (size_t)NN*4;         // scores [NN] f32
static constexpr size_t OFF_ES   = OFF_SC   + (size_t)NN*4;         // es     [NE] int2 {col, val bits}
static constexpr size_t OFF_CNT  = OFF_ES   + (size_t)NE*8;         // counts [NN] i32
static constexpr size_t OFF_RP   = OFF_CNT  + (size_t)NN*4;         // rowptr [NN+1] i32
static constexpr size_t OFF_CUR  = OFF_RP   + (size_t)(NN+64)*4;    // cursor [NN] i32
static constexpr size_t OFF_BS   = OFF_CUR  + (size_t)NN*4;         // block sums [128] i32
static constexpr size_t OFF_RED  = OFF_BS   + 512;                  // red[8]: per-layer {unused,sum}
static constexpr size_t OFF_FLAG = OFF_RED  + 64;                   // dtype flags [4] i32 (1=f32, 0=bf16)
static constexpr size_t OFF_WAT  = OFF_FLAG + 16;                   // w_att f32 [100]
static constexpr size_t OFF_WBF  = OFF_WAT  + 512;                  // W bf16 [3][112][128] zero-padded

// dtype-flexible scalar load (prologue kernels only)
__device__ inline float ldf(const void* p, int i, int f32) {
    return f32 ? ((const float*)p)[i]
               : __bfloat162float(((const __hip_bfloat16*)p)[i]);
}

// unpack a packed pair of bf16 (little-endian: low ushort = element 0)
__device__ inline float bflo(unsigned int u) { return __uint_as_float(u << 16); }
__device__ inline float bfhi(unsigned int u) { return __uint_as_float(u & 0xFFFF0000u); }
// pack two floats to bf16 pair (RNE via __float2bfloat16)
__device__ inline unsigned int pack2bf(float a, float b) {
    __hip_bfloat16 ha = __float2bfloat16(a), hb = __float2bfloat16(b);
    unsigned short ua = *(unsigned short*)&ha, ub = *(unsigned short*)&hb;
    return (unsigned int)ua | ((unsigned int)ub << 16);
}

// ---------------- dtype probe ----------------
// Probe EVEN uint16 halves (low mantissa bits of f32 = uniform garbage,
// ~48% decode with exponent>=134; genuine bf16 data never has |v|>=128).
__global__ __launch_bounds__(64) void k_probe(const void* emb, const void* aval,
                                              const void* watt, const void* witm,
                                              int* flags) {
    int t = threadIdx.x;
    if (t >= 4) return;
    const void* ptrs[4] = {emb, aval, watt, witm};
    const int   ns[4]   = {256, 256, 50, 256};
    const unsigned short* h = (const unsigned short*)ptrs[t];
    int big = 0;
    for (int i = 0; i < ns[t]; i++) {
        int ex = (h[2 * i] >> 7) & 0xFF;
        if (ex >= 134) big++;
    }
    flags[t] = (big >= 2) ? 1 : 0;
}

// ---------------- init / convert ----------------
__global__ __launch_bounds__(256) void k_init(float* deg, int* counts, float* red) {
    int i = blockIdx.x * 256 + threadIdx.x;
    if (i < NN) { deg[i] = 0.f; counts[i] = 0; }
    if (i < 8)  { red[i] = 0.f; }   // [2l+1] = softmax denom accumulator
}

// wat f32 + W -> bf16 [3][112][128], zeros outside 100x100 (MFMA padding).
__global__ __launch_bounds__(256) void k_cvt(const void* w_att, const void* w_itm,
                                             const int* flags, float* wat,
                                             unsigned short* wbf) {
    int i = blockIdx.x * 256 + threadIdx.x;
    if (i < NL * 112 * 128) {
        int l = i / (112 * 128), rem = i % (112 * 128);
        int n = rem >> 7, k = rem & 127;
        float v = (n < EM && k < EM) ? ldf(w_itm, (l * EM + n) * EM + k, flags[3]) : 0.f;
        __hip_bfloat16 b = __float2bfloat16(v);
        wbf[i] = *(unsigned short*)&b;
    }
    if (i < EM) wat[i] = ldf(w_att, i, flags[2]);
}

// wave-per-row: xbf=emb (bf16, K-padded to 128), fin=emb (bf16),
// scores[r]=dot(emb_row, w_att). (b_att omitted: softmax shift-invariant.)
__global__ __launch_bounds__(256) void k_initxf(const void* __restrict__ emb, const int* flags,
                                                const float* __restrict__ wat,
                                                unsigned int* __restrict__ xbf,
                                                unsigned int* __restrict__ fin,
                                                float* __restrict__ scores) {
    int lane = threadIdx.x & 63, w = threadIdx.x >> 6;
    int r = blockIdx.x * 4 + w;
    if (r >= NN) return;
    float f0 = 0.f, f1 = 0.f, part = 0.f;
    bool act = lane < 50;
    if (act) {
        if (flags[0]) {
            float2 t = ((const float2*)emb)[(size_t)r * 50 + lane];
            f0 = t.x; f1 = t.y;
        } else {
            unsigned int u = ((const unsigned int*)emb)[(size_t)r * 50 + lane];
            f0 = bflo(u); f1 = bfhi(u);
        }
        float2 wv = *(const float2*)(wat + 2 * lane);
        part = f0 * wv.x + f1 * wv.y;
        fin[(size_t)r * 50 + lane] = pack2bf(f0, f1);
    }
    xbf[(size_t)r * 64 + lane] = act ? pack2bf(f0, f1) : 0u;  // lanes 50..63 = K pad
    #pragma unroll
    for (int off = 32; off; off >>= 1) part += __shfl_xor(part, off);
    if (lane == 0) scores[r] = part;
}

// ---------------- degree + row histogram ----------------
__global__ __launch_bounds__(256) void k_deg(const void* __restrict__ val,
                                             const int* __restrict__ row, const int* __restrict__ col,
                                             const int* flags, float* deg, int* counts) {
    int e = blockIdx.x * 256 + threadIdx.x;
    if (e >= NE) return;
    atomicAdd(&deg[col[e]], ldf(val, e, flags[1]));
    atomicAdd(&counts[row[e]], 1);
}

// ---------------- exclusive scan of counts -> rowptr (3 kernels) ----------------
__global__ __launch_bounds__(256) void k_scanA(const int* __restrict__ counts, int* excl, int* bsum) {
    __shared__ int s[256];
    int base = blockIdx.x * 1024;
    int tid = threadIdx.x;
    int v[4]; int t = 0;
    #pragma unroll
    for (int i = 0; i < 4; i++) {
        int idx = base + tid * 4 + i;
        v[i] = (idx < NN) ? counts[idx] : 0;
        t += v[i];
    }
    s[tid] = t; __syncthreads();
    for (int off = 1; off < 256; off <<= 1) {
        int add = (tid >= off) ? s[tid - off] : 0;
        __syncthreads();
        s[tid] += add;
        __syncthreads();
    }
    int ex = (tid == 0) ? 0 : s[tid - 1];
    #pragma unroll
    for (int i = 0; i < 4; i++) {
        int idx = base + tid * 4 + i;
        if (idx < NN) excl[idx] = ex;
        ex += v[i];
    }
    if (tid == 255) bsum[blockIdx.x] = s[255];
}

__global__ __launch_bounds__(64) void k_scanB(int* bsum, int nb) {
    if (threadIdx.x == 0) {
        int run = 0;
        for (int i = 0; i < nb; i++) { int t = bsum[i]; bsum[i] = run; run += t; }
    }
}

__global__ __launch_bounds__(256) void k_scanC(int* rowptr, int* cursor, const int* __restrict__ bsum) {
    int i = blockIdx.x * 256 + threadIdx.x;
    if (i >= NN) return;
    int v = rowptr[i] + bsum[i >> 10];
    rowptr[i] = v; cursor[i] = v;
    if (i == 0) rowptr[NN] = NE;
}

// scatter edges into CSR order; packs {col, val/deg[col]} into one int2.
__global__ __launch_bounds__(256) void k_scatter(const int* __restrict__ row, const int* __restrict__ col,
                                                 const void* __restrict__ aval, const int* flags,
                                                 const float* __restrict__ deg, int* cursor,
                                                 int2* es) {
    int e = blockIdx.x * 256 + threadIdx.x;
    if (e >= NE) return;
    int r = row[e];
    int c = col[e];
    int pos = atomicAdd(&cursor[r], 1);
    float v = ldf(aval, e, flags[1]) / deg[c];
    es[pos] = make_int2(c, __float_as_int(v));
}

// exp (no max subtraction: scores bounded, softmax identical) + global sum.
__global__ __launch_bounds__(256) void k_expsum(float* __restrict__ scores, float* red, int layer) {
    __shared__ float ss[4];
    int n = blockIdx.x * 256 + threadIdx.x;
    float p = 0.f;
    if (n < NN) { p = expf(scores[n]); scores[n] = p; }
    float t = p;
    #pragma unroll
    for (int off = 32; off; off >>= 1) t += __shfl_xor(t, off);
    if ((threadIdx.x & 63) == 0) ss[threadIdx.x >> 6] = t;
    __syncthreads();
    if (threadIdx.x == 0) atomicAdd(&red[2 * layer + 1], ss[0] + ss[1] + ss[2] + ss[3]);
}

// ---------------- per-layer: m = bf16((x @ W^T) * attw) via MFMA ----------------
// Round-9: replaces the LDS-tiled f32 gemm (82us, 1.4e7 LDS bank conflicts from
// the 64-way-conflicting transpose staging). One wave per 16 rows; K=100 padded
// to 128 (4x mfma_f32_16x16x32_bf16); N=100 as 7x16 tiles (col<100 guard).
// Fragment maps (verified, learn_hip m89/m91/m120): A[m=lane&15][k=quad*8+j],
// B[n=lane&15][k=quad*8+j], C/D col=lane&15, row=quad*4+reg.
// No LDS, no barriers; W (28KB/layer) is L1/L2-hot.
__global__ __launch_bounds__(256) void k_gemm(const unsigned short* __restrict__ xbf,
                                              const unsigned short* __restrict__ wbf,
                                              const float* __restrict__ scores,
                                              const float* __restrict__ red,
                                              unsigned short* __restrict__ m, int layer) {
    int wid = threadIdx.x >> 6, lane = threadIdx.x & 63;
    int row0 = blockIdx.x * 64 + wid * 16;
    if (row0 >= NN) return;                 // NN = 16*6250: no partial row tiles
    int c15 = lane & 15, quad = lane >> 4;
    float inv_sum = 1.0f / red[2 * layer + 1];

    const bf16x8* xa = (const bf16x8*)(xbf + (size_t)(row0 + c15) * 128 + quad * 8);
    bf16x8 a[4];
    #pragma unroll
    for (int kq = 0; kq < 4; kq++) a[kq] = xa[kq * 4];   // +32 bf16 per kq

    float att[4];
    #pragma unroll
    for (int r = 0; r < 4; r++) att[r] = scores[row0 + quad * 4 + r] * inv_sum;

    const bf16x8* wb = (const bf16x8*)(wbf + (size_t)layer * 112 * 128
                                       + (size_t)c15 * 128 + quad * 8);
    #pragma unroll
    for (int nt = 0; nt < 7; nt++) {
        f32x4 acc = {0.f, 0.f, 0.f, 0.f};
        #pragma unroll
        for (int kq = 0; kq < 4; kq++) {
            bf16x8 b = wb[nt * 256 + kq * 4];   // +16 rows*128 per nt, +32 bf16 per kq
            acc = __builtin_amdgcn_mfma_f32_16x16x32_bf16(a[kq], b, acc, 0, 0, 0);
        }
        int col = nt * 16 + c15;
        if (col < EM) {
            #pragma unroll
            for (int r = 0; r < 4; r++) {
                int grow = row0 + quad * 4 + r;
                __hip_bfloat16 bv = __float2bfloat16(acc[r] * att[r]);
                m[(size_t)grow * EM + col] = *(unsigned short*)&bv;
            }
        }
    }
}

// ---------------- per-layer: SpMM (bf16 gather, CSR) fused with L2-normalize,
// final += (bf16 rmw), next-layer scores, and (last layer) output write.
// Predicated unroll-4 edge loop: 4 independent gathers in flight per batch.
__global__ __launch_bounds__(256) void k_spmm(const int* __restrict__ rowptr,
                                              const int2* __restrict__ es,
                                              const unsigned short* __restrict__ m,
                                              const float* __restrict__ wat,
                                              unsigned int* __restrict__ xbf,
                                              unsigned int* __restrict__ fin,
                                              float* __restrict__ scores,
                                              void* __restrict__ out, const int* flags, int last) {
    int lane = threadIdx.x & 63;
    int w = threadIdx.x >> 6;
    int r = blockIdx.x * 4 + w;
    if (r >= NN) return;
    int s = rowptr[r], e = rowptr[r + 1];
    bool act = lane < 50;
    float a0 = 0.f, a1 = 0.f, b0 = 0.f, b1 = 0.f;
    for (int i = s; i < e; i += 4) {
        int2 cv[4];
        cv[0] = es[i];
        #pragma unroll
        for (int j = 1; j < 4; j++)
            cv[j] = (i + j < e) ? es[i + j] : make_int2(cv[0].x, 0);
        unsigned int u[4] = {0u, 0u, 0u, 0u};
        if (act) {
            #pragma unroll
            for (int j = 0; j < 4; j++)
                u[j] = *(const unsigned int*)(m + (size_t)cv[j].x * EM + 2 * lane);
        }
        float v0 = __int_as_float(cv[0].y), v1 = __int_as_float(cv[1].y);
        float v2 = __int_as_float(cv[2].y), v3 = __int_as_float(cv[3].y);
        a0 += v0 * bflo(u[0]); a1 += v0 * bfhi(u[0]);
        b0 += v1 * bflo(u[1]); b1 += v1 * bfhi(u[1]);
        a0 += v2 * bflo(u[2]); a1 += v2 * bfhi(u[2]);
        b0 += v3 * bflo(u[3]); b1 += v3 * bfhi(u[3]);
    }
    a0 += b0; a1 += b1;
    float sq = a0 * a0 + a1 * a1;
    #pragma unroll
    for (int off = 32; off; off >>= 1) sq += __shfl_xor(sq, off);
    float rn = 1.f / fmaxf(sqrtf(sq), 1e-12f);
    float n0 = a0 * rn, n1 = a1 * rn;   // lanes >=50: a0=a1=0 -> n0=n1=0 (K pad)

    float part = 0.f;
    if (!last) xbf[(size_t)r * 64 + lane] = pack2bf(n0, n1);
    if (act) {
        size_t pidx = (size_t)r * 50 + lane;
        unsigned int fu = fin[pidx];
        float fn0 = bflo(fu) + n0, fn1 = bfhi(fu) + n1;
        if (!last) {
            fin[pidx] = pack2bf(fn0, fn1);
            float2 wv = *(const float2*)(wat + 2 * lane);
            part = n0 * wv.x + n1 * wv.y;
        } else {
            float o0 = fn0 * 0.25f, o1 = fn1 * 0.25f;
            if (flags[0]) ((float2*)out)[pidx] = make_float2(o0, o1);
            else          ((unsigned int*)out)[pidx] = pack2bf(o0, o1);
        }
    }
    if (!last) {
        #pragma unroll
        for (int off = 32; off; off >>= 1) part += __shfl_xor(part, off);
        if (lane == 0) scores[r] = part;
    }
}

extern "C" void kernel_launch(void* const* d_in, const int* in_sizes, int n_in,
                              void* d_out, int out_size, void* d_ws, size_t ws_size,
                              hipStream_t stream) {
    const void* emb   = d_in[0];
    const void* aval  = d_in[1];
    const void* w_att = d_in[2];
    const void* w_itm = d_in[4];
    const int* arow = (const int*)d_in[5];
    const int* acol = (const int*)d_in[6];

    char* w = (char*)d_ws;
    unsigned int*   xbf    = (unsigned int*)(w + OFF_XB);
    unsigned short* m      = (unsigned short*)(w + OFF_M);
    unsigned int*   fin    = (unsigned int*)(w + OFF_F);
    float*          deg    = (float*)(w + OFF_DEG);
    float*          scores = (float*)(w + OFF_SC);
    int2*           es     = (int2*) (w + OFF_ES);
    int*            counts = (int*)  (w + OFF_CNT);
    int*            rowptr = (int*)  (w + OFF_RP);
    int*            cursor = (int*)  (w + OFF_CUR);
    int*            bsum   = (int*)  (w + OFF_BS);
    float*          red    = (float*)(w + OFF_RED);
    int*            flags  = (int*)  (w + OFF_FLAG);
    float*          wat    = (float*)(w + OFF_WAT);
    unsigned short* wbf    = (unsigned short*)(w + OFF_WBF);

    const int GN   = (NN + 255) / 256;        // 391
    const int GNE  = (NE + 255) / 256;        // 3125
    const int GSCN = (NN + 1023) / 1024;      // 98 scan blocks
    const int GW4  = (NN + 3) / 4;            // 25000 (wave-per-node kernels)
    const int GGE  = (NN + 63) / 64;          // 1563 gemm blocks (64 rows each)
    const int GCVT = (NL * 112 * 128 + 255) / 256;  // 168

    k_probe<<<1, 64, 0, stream>>>(emb, aval, w_att, w_itm, flags);
    k_init<<<GN, 256, 0, stream>>>(deg, counts, red);
    k_cvt<<<GCVT, 256, 0, stream>>>(w_att, w_itm, flags, wat, wbf);
    k_initxf<<<GW4, 256, 0, stream>>>(emb, flags, wat, xbf, fin, scores);
    k_deg<<<GNE, 256, 0, stream>>>(aval, arow, acol, flags, deg, counts);
    k_scanA<<<GSCN, 256, 0, stream>>>(counts, rowptr, bsum);
    k_scanB<<<1, 64, 0, stream>>>(bsum, GSCN);
    k_scanC<<<GN, 256, 0, stream>>>(rowptr, cursor, bsum);
    k_scatter<<<GNE, 256, 0, stream>>>(arow, acol, aval, flags, deg, cursor, es);

    for (int l = 0; l < NL; l++) {
        k_expsum<<<GN, 256, 0, stream>>>(scores, red, l);
        k_gemm<<<GGE, 256, 0, stream>>>((const unsigned short*)xbf, wbf, scores, red, m, l);
        k_spmm<<<GW4, 256, 0, stream>>>(rowptr, es, m, wat, xbf, fin, scores,
                                        d_out, flags, (l == NL - 1) ? 1 : 0);
    }
}

// Round 10
// 589.298 us; speedup vs baseline: 5.1538x; 1.0260x over previous
//
#include <hip/hip_runtime.h>
#include <hip/hip_bf16.h>

// Problem constants (fixed by reference)
#define NN 100000      // nodes
#define NE 800000      // edges
#define EM 100         // embedding dim
#define NL 3           // layers

typedef short bf16x8 __attribute__((ext_vector_type(8)));
typedef float f32x4  __attribute__((ext_vector_type(4)));

// ---------------- workspace layout (bytes) ----------------
static constexpr size_t OFF_XB   = 0;                               // xbf [NN*128] bf16 (K-padded rows)
static constexpr size_t OFF_M    = OFF_XB   + (size_t)NN*128*2;     // m   [NN*100] bf16
static constexpr size_t OFF_F    = OFF_M    + (size_t)NN*EM*2;      // fin [NN*50] uint (bf16x2)
static constexpr size_t OFF_DEG  = OFF_F    + (size_t)NN*EM*2;      // degree [NN] f32
static constexpr size_t OFF_SC   = OFF_DEG  + (size_t)NN*4;         // scores [NN] f32
static constexpr size_t OFF_ES   = OFF_SC   + (size_t)NN*4;         // es     [NE] int2 {col, val bits}
static constexpr size_t OFF_CNT  = OFF_ES   + (size_t)NE*8;         // counts [NN] i32
static constexpr size_t OFF_RP   = OFF_CNT  + (size_t)NN*4;         // rowptr [NN+1] i32
static constexpr size_t OFF_CUR  = OFF_RP   + (size_t)(NN+64)*4;    // cursor [NN] i32
static constexpr size_t OFF_BS   = OFF_CUR  + (size_t)NN*4;         // block sums [128] i32
static constexpr size_t OFF_RED  = OFF_BS   + 512;                  // red[8]: per-layer {unused,sum}
static constexpr size_t OFF_FLAG = OFF_RED  + 64;                   // flags [4] i32 (flags[0]=emb is f32)
static constexpr size_t OFF_WAT  = OFF_FLAG + 16;                   // w_att f32 [100]
static constexpr size_t OFF_WBF  = OFF_WAT  + 512;                  // W bf16 [3][112][128] zero-padded

// dtype-flexible scalar load (prologue kernels only)
__device__ inline float ldf(const void* p, int i, int f32) {
    return f32 ? ((const float*)p)[i]
               : __bfloat162float(((const __hip_bfloat16*)p)[i]);
}

// unpack a packed pair of bf16 (little-endian: low ushort = element 0)
__device__ inline float bflo(unsigned int u) { return __uint_as_float(u << 16); }
__device__ inline float bfhi(unsigned int u) { return __uint_as_float(u & 0xFFFF0000u); }
// pack two floats to bf16 pair (RNE via __float2bfloat16)
__device__ inline unsigned int pack2bf(float a, float b) {
    __hip_bfloat16 ha = __float2bfloat16(a), hb = __float2bfloat16(b);
    unsigned short ua = *(unsigned short*)&ha, ub = *(unsigned short*)&hb;
    return (unsigned int)ua | ((unsigned int)ub << 16);
}

// ---------------- inline dtype probe (per block, wave 0, LDS broadcast) ----------
// Even uint16 halves: for f32 data these are low mantissa bits (uniform garbage,
// ~48% with exponent>=134); genuine bf16 data here never reaches |v|>=128.
// Call before any divergent return (contains __syncthreads).
__device__ inline int probe_block(const void* p, int nsamp) {
    __shared__ int sflag;
    int tid = threadIdx.x;
    if (tid < 64) {
        const unsigned short* h = (const unsigned short*)p;
        int big = 0;
        for (int i = tid; i < nsamp; i += 64) {
            int ex = (h[2 * i] >> 7) & 0xFF;
            big += (ex >= 134) ? 1 : 0;
        }
        #pragma unroll
        for (int off = 32; off; off >>= 1) big += __shfl_xor(big, off);
        if (tid == 0) sflag = (big >= 2) ? 1 : 0;
    }
    __syncthreads();
    int f = sflag;
    __syncthreads();   // safe against a subsequent probe_block overwriting sflag
    return f;
}

// ---------------- setup: zero deg/counts/red + convert wat/W(bf16, padded) ------
__global__ __launch_bounds__(256) void k_setup(const void* w_att, const void* w_itm,
                                               float* deg, int* counts, float* red,
                                               float* wat, unsigned short* wbf) {
    int fw = probe_block(w_att, 50);
    int fi = probe_block(w_itm, 256);
    int i = blockIdx.x * 256 + threadIdx.x;
    if (i < NN) { deg[i] = 0.f; counts[i] = 0; }
    if (i < 8)  red[i] = 0.f;
    if (i < EM) wat[i] = ldf(w_att, i, fw);
    if (i < NL * 112 * 128) {
        int l = i / (112 * 128), rem = i % (112 * 128);
        int n = rem >> 7, k = rem & 127;
        float v = (n < EM && k < EM) ? ldf(w_itm, (l * EM + n) * EM + k, fi) : 0.f;
        __hip_bfloat16 b = __float2bfloat16(v);
        wbf[i] = *(unsigned short*)&b;
    }
}

// wave-per-row: xbf=emb (bf16, K-padded to 128), fin=emb (bf16),
// scores[r]=dot(emb_row, w_att). (b_att omitted: softmax shift-invariant.)
// Publishes flags[0] (emb dtype) for the last-layer output-store branch.
__global__ __launch_bounds__(256) void k_initxf(const void* __restrict__ emb,
                                                const float* __restrict__ wat,
                                                unsigned int* __restrict__ xbf,
                                                unsigned int* __restrict__ fin,
                                                float* __restrict__ scores, int* flags) {
    int femb = probe_block(emb, 256);
    if (blockIdx.x == 0 && threadIdx.x == 0) flags[0] = femb;
    int lane = threadIdx.x & 63, w = threadIdx.x >> 6;
    int r = blockIdx.x * 4 + w;
    if (r >= NN) return;
    float f0 = 0.f, f1 = 0.f, part = 0.f;
    bool act = lane < 50;
    if (act) {
        if (femb) {
            float2 t = ((const float2*)emb)[(size_t)r * 50 + lane];
            f0 = t.x; f1 = t.y;
        } else {
            unsigned int u = ((const unsigned int*)emb)[(size_t)r * 50 + lane];
            f0 = bflo(u); f1 = bfhi(u);
        }
        float2 wv = *(const float2*)(wat + 2 * lane);
        part = f0 * wv.x + f1 * wv.y;
        fin[(size_t)r * 50 + lane] = pack2bf(f0, f1);
    }
    xbf[(size_t)r * 64 + lane] = act ? pack2bf(f0, f1) : 0u;  // lanes 50..63 = K pad
    #pragma unroll
    for (int off = 32; off; off >>= 1) part += __shfl_xor(part, off);
    if (lane == 0) scores[r] = part;
}

// ---------------- degree + row histogram ----------------
__global__ __launch_bounds__(256) void k_deg(const void* __restrict__ val,
                                             const int* __restrict__ row, const int* __restrict__ col,
                                             float* deg, int* counts) {
    int fav = probe_block(val, 256);
    int e = blockIdx.x * 256 + threadIdx.x;
    if (e >= NE) return;
    atomicAdd(&deg[col[e]], ldf(val, e, fav));
    atomicAdd(&counts[row[e]], 1);
}

// ---------------- exclusive scan of counts -> rowptr (2 kernels) ----------------
__global__ __launch_bounds__(256) void k_scanA(const int* __restrict__ counts, int* excl, int* bsum) {
    __shared__ int s[256];
    int base = blockIdx.x * 1024;
    int tid = threadIdx.x;
    int v[4]; int t = 0;
    #pragma unroll
    for (int i = 0; i < 4; i++) {
        int idx = base + tid * 4 + i;
        v[i] = (idx < NN) ? counts[idx] : 0;
        t += v[i];
    }
    s[tid] = t; __syncthreads();
    for (int off = 1; off < 256; off <<= 1) {
        int add = (tid >= off) ? s[tid - off] : 0;
        __syncthreads();
        s[tid] += add;
        __syncthreads();
    }
    int ex = (tid == 0) ? 0 : s[tid - 1];
    #pragma unroll
    for (int i = 0; i < 4; i++) {
        int idx = base + tid * 4 + i;
        if (idx < NN) excl[idx] = ex;
        ex += v[i];
    }
    if (tid == 255) bsum[blockIdx.x] = s[255];
}

// adds the bsum prefix (computed per block by wave 0 -- <=97 entries) and
// initializes cursor. Replaces the old serial single-block scanB.
__global__ __launch_bounds__(256) void k_scanC(int* rowptr, int* cursor, const int* __restrict__ bsum) {
    __shared__ int spfx;
    int tid = threadIdx.x;
    int gi = blockIdx.x >> 2;   // this block's 1024-group index
    if (tid < 64) {
        int t = (tid < gi) ? bsum[tid] : 0;
        if (tid + 64 < gi) t += bsum[tid + 64];
        #pragma unroll
        for (int off = 32; off; off >>= 1) t += __shfl_xor(t, off);
        if (tid == 0) spfx = t;
    }
    __syncthreads();
    int pfx = spfx;
    int i = blockIdx.x * 256 + tid;
    if (i < NN) {
        int v = rowptr[i] + pfx;
        rowptr[i] = v; cursor[i] = v;
        if (i == 0) rowptr[NN] = NE;
    }
}

// scatter edges into CSR order; packs {col, val/deg[col]} into one int2.
__global__ __launch_bounds__(256) void k_scatter(const int* __restrict__ row, const int* __restrict__ col,
                                                 const void* __restrict__ aval,
                                                 const float* __restrict__ deg, int* cursor,
                                                 int2* es) {
    int fav = probe_block(aval, 256);
    int e = blockIdx.x * 256 + threadIdx.x;
    if (e >= NE) return;
    int r = row[e];
    int c = col[e];
    int pos = atomicAdd(&cursor[r], 1);
    float v = ldf(aval, e, fav) / deg[c];
    es[pos] = make_int2(c, __float_as_int(v));
}

// exp (no max subtraction: scores bounded, softmax identical) + global sum.
__global__ __launch_bounds__(256) void k_expsum(float* __restrict__ scores, float* red, int layer) {
    __shared__ float ss[4];
    int n = blockIdx.x * 256 + threadIdx.x;
    float p = 0.f;
    if (n < NN) { p = expf(scores[n]); scores[n] = p; }
    float t = p;
    #pragma unroll
    for (int off = 32; off; off >>= 1) t += __shfl_xor(t, off);
    if ((threadIdx.x & 63) == 0) ss[threadIdx.x >> 6] = t;
    __syncthreads();
    if (threadIdx.x == 0) atomicAdd(&red[2 * layer + 1], ss[0] + ss[1] + ss[2] + ss[3]);
}

// ---------------- per-layer: m = bf16((x @ W^T) * attw) via MFMA ----------------
// One wave per 16 rows; K=100 padded to 128 (4x mfma_f32_16x16x32_bf16);
// N=100 as 7x16 tiles (col<100 guard). Fragment maps (learn_hip m89/m91/m120):
// A[m=lane&15][k=quad*8+j], B[n=lane&15][k=quad*8+j], C/D col=lane&15,
// row=quad*4+reg. No LDS, no barriers; W (28KB/layer) is L1/L2-hot.
__global__ __launch_bounds__(256) void k_gemm(const unsigned short* __restrict__ xbf,
                                              const unsigned short* __restrict__ wbf,
                                              const float* __restrict__ scores,
                                              const float* __restrict__ red,
                                              unsigned short* __restrict__ m, int layer) {
    int wid = threadIdx.x >> 6, lane = threadIdx.x & 63;
    int row0 = blockIdx.x * 64 + wid * 16;
    if (row0 >= NN) return;                 // NN = 16*6250: no partial row tiles
    int c15 = lane & 15, quad = lane >> 4;
    float inv_sum = 1.0f / red[2 * layer + 1];

    const bf16x8* xa = (const bf16x8*)(xbf + (size_t)(row0 + c15) * 128 + quad * 8);
    bf16x8 a[4];
    #pragma unroll
    for (int kq = 0; kq < 4; kq++) a[kq] = xa[kq * 4];   // +32 bf16 per kq

    float att[4];
    #pragma unroll
    for (int r = 0; r < 4; r++) att[r] = scores[row0 + quad * 4 + r] * inv_sum;

    const bf16x8* wb = (const bf16x8*)(wbf + (size_t)layer * 112 * 128
                                       + (size_t)c15 * 128 + quad * 8);
    #pragma unroll
    for (int nt = 0; nt < 7; nt++) {
        f32x4 acc = {0.f, 0.f, 0.f, 0.f};
        #pragma unroll
        for (int kq = 0; kq < 4; kq++) {
            bf16x8 b = wb[nt * 256 + kq * 4];   // +16 rows*128 per nt, +32 bf16 per kq
            acc = __builtin_amdgcn_mfma_f32_16x16x32_bf16(a[kq], b, acc, 0, 0, 0);
        }
        int col = nt * 16 + c15;
        if (col < EM) {
            #pragma unroll
            for (int r = 0; r < 4; r++) {
                int grow = row0 + quad * 4 + r;
                __hip_bfloat16 bv = __float2bfloat16(acc[r] * att[r]);
                m[(size_t)grow * EM + col] = *(unsigned short*)&bv;
            }
        }
    }
}

// ---------------- per-layer: SpMM (bf16 gather, CSR) fused with L2-normalize,
// final += (bf16 rmw), next-layer scores, and (last layer) output write.
// Predicated unroll-8 edge loop: 8 independent gathers in flight per batch
// (degree ~ Poisson(8): 59% of rows finish in one batch). Out-of-range slots
// reuse the batch's first column with weight 0 (no serial remainder).
__global__ __launch_bounds__(256) void k_spmm(const int* __restrict__ rowptr,
                                              const int2* __restrict__ es,
                                              const unsigned short* __restrict__ m,
                                              const float* __restrict__ wat,
                                              unsigned int* __restrict__ xbf,
                                              unsigned int* __restrict__ fin,
                                              float* __restrict__ scores,
                                              void* __restrict__ out, const int* flags, int last) {
    int lane = threadIdx.x & 63;
    int w = threadIdx.x >> 6;
    int r = blockIdx.x * 4 + w;
    if (r >= NN) return;
    int s = rowptr[r], e = rowptr[r + 1];
    bool act = lane < 50;
    float a0 = 0.f, a1 = 0.f, b0 = 0.f, b1 = 0.f;
    for (int i = s; i < e; i += 8) {
        int2 cv[8];
        cv[0] = es[i];
        #pragma unroll
        for (int j = 1; j < 8; j++)
            cv[j] = (i + j < e) ? es[i + j] : make_int2(cv[0].x, 0);
        unsigned int u[8] = {0u, 0u, 0u, 0u, 0u, 0u, 0u, 0u};
        if (act) {
            #pragma unroll
            for (int j = 0; j < 8; j++)
                u[j] = *(const unsigned int*)(m + (size_t)cv[j].x * EM + 2 * lane);
        }
        #pragma unroll
        for (int j = 0; j < 8; j += 2) {
            float va = __int_as_float(cv[j].y), vb = __int_as_float(cv[j + 1].y);
            a0 += va * bflo(u[j]);     a1 += va * bfhi(u[j]);
            b0 += vb * bflo(u[j + 1]); b1 += vb * bfhi(u[j + 1]);
        }
    }
    a0 += b0; a1 += b1;
    float sq = a0 * a0 + a1 * a1;
    #pragma unroll
    for (int off = 32; off; off >>= 1) sq += __shfl_xor(sq, off);
    float rn = 1.f / fmaxf(sqrtf(sq), 1e-12f);
    float n0 = a0 * rn, n1 = a1 * rn;   // lanes >=50: a0=a1=0 -> n0=n1=0 (K pad)

    float part = 0.f;
    if (!last) xbf[(size_t)r * 64 + lane] = pack2bf(n0, n1);
    if (act) {
        size_t pidx = (size_t)r * 50 + lane;
        unsigned int fu = fin[pidx];
        float fn0 = bflo(fu) + n0, fn1 = bfhi(fu) + n1;
        if (!last) {
            fin[pidx] = pack2bf(fn0, fn1);
            float2 wv = *(const float2*)(wat + 2 * lane);
            part = n0 * wv.x + n1 * wv.y;
        } else {
            float o0 = fn0 * 0.25f, o1 = fn1 * 0.25f;
            if (flags[0]) ((float2*)out)[pidx] = make_float2(o0, o1);
            else          ((unsigned int*)out)[pidx] = pack2bf(o0, o1);
        }
    }
    if (!last) {
        #pragma unroll
        for (int off = 32; off; off >>= 1) part += __shfl_xor(part, off);
        if (lane == 0) scores[r] = part;
    }
}

extern "C" void kernel_launch(void* const* d_in, const int* in_sizes, int n_in,
                              void* d_out, int out_size, void* d_ws, size_t ws_size,
                              hipStream_t stream) {
    const void* emb   = d_in[0];
    const void* aval  = d_in[1];
    const void* w_att = d_in[2];
    const void* w_itm = d_in[4];
    const int* arow = (const int*)d_in[5];
    const int* acol = (const int*)d_in[6];

    char* w = (char*)d_ws;
    unsigned int*   xbf    = (unsigned int*)(w + OFF_XB);
    unsigned short* m      = (unsigned short*)(w + OFF_M);
    unsigned int*   fin    = (unsigned int*)(w + OFF_F);
    float*          deg    = (float*)(w + OFF_DEG);
    float*          scores = (float*)(w + OFF_SC);
    int2*           es     = (int2*) (w + OFF_ES);
    int*            counts = (int*)  (w + OFF_CNT);
    int*            rowptr = (int*)  (w + OFF_RP);
    int*            cursor = (int*)  (w + OFF_CUR);
    int*            bsum   = (int*)  (w + OFF_BS);
    float*          red    = (float*)(w + OFF_RED);
    int*            flags  = (int*)  (w + OFF_FLAG);
    float*          wat    = (float*)(w + OFF_WAT);
    unsigned short* wbf    = (unsigned short*)(w + OFF_WBF);

    const int GN   = (NN + 255) / 256;        // 391
    const int GNE  = (NE + 255) / 256;        // 3125
    const int GSCN = (NN + 1023) / 1024;      // 98 scan blocks
    const int GW4  = (NN + 3) / 4;            // 25000 (wave-per-node kernels)
    const int GGE  = (NN + 63) / 64;          // 1563 gemm blocks (64 rows each)

    k_setup<<<GN, 256, 0, stream>>>(w_att, w_itm, deg, counts, red, wat, wbf);
    k_initxf<<<GW4, 256, 0, stream>>>(emb, wat, xbf, fin, scores, flags);
    k_deg<<<GNE, 256, 0, stream>>>(aval, arow, acol, deg, counts);
    k_scanA<<<GSCN, 256, 0, stream>>>(counts, rowptr, bsum);
    k_scanC<<<GN, 256, 0, stream>>>(rowptr, cursor, bsum);
    k_scatter<<<GNE, 256, 0, stream>>>(arow, acol, aval, deg, cursor, es);

    for (int l = 0; l < NL; l++) {
        k_expsum<<<GN, 256, 0, stream>>>(scores, red, l);
        k_gemm<<<GGE, 256, 0, stream>>>((const unsigned short*)xbf, wbf, scores, red, m, l);
        k_spmm<<<GW4, 256, 0, stream>>>(rowptr, es, m, wat, xbf, fin, scores,
                                        d_out, flags, (l == NL - 1) ? 1 : 0);
    }
}